// Round 4
// baseline (1167.829 us; speedup 1.0000x reference)
//
#include <hip/hip_runtime.h>

typedef unsigned int u32;
typedef unsigned short u16;
typedef unsigned long long u64;
typedef __bf16 bf16x8 __attribute__((ext_vector_type(8)));
typedef float f32x4 __attribute__((ext_vector_type(4)));

#define DEVI __device__ __forceinline__

DEVI u16 f2bf(float x){ u32 u = __builtin_bit_cast(u32, x); return (u16)((u + 0x7fffu + ((u>>16)&1u)) >> 16); }
DEVI float bf2f(u16 h){ return __builtin_bit_cast(float, ((u32)h)<<16); }

DEVI void gload_lds16(const void* g, void* l){
  __builtin_amdgcn_global_load_lds((const __attribute__((address_space(1))) void*)g,
                                   (__attribute__((address_space(3))) void*)l, 16, 0, 0);
}

// constants
#define NB 1024
#define ND 768
#define NM 50000
#define NK 50
#define NH 8
#define SAMP 4096
#define RSEL 25
#define CAP 2048

// ---------------- prep: wave-per-row f32 -> bf16 + sumsq ----------------
__global__ __launch_bounds__(256) void prep_mk(const float* __restrict__ src, u16* __restrict__ dst,
                                               float* __restrict__ nrm2){
  int r = blockIdx.x*4 + (threadIdx.x>>6);
  int l = threadIdx.x & 63;
  const float4* s4 = (const float4*)(src + (long)r*ND);
  u32* d = (u32*)(dst + (long)r*ND);
  float ss = 0.f;
  #pragma unroll
  for (int j=0;j<3;j++){
    float4 v = s4[l + j*64];
    ss += v.x*v.x + v.y*v.y + v.z*v.z + v.w*v.w;
    d[(l+j*64)*2]   = ((u32)f2bf(v.y)<<16) | f2bf(v.x);
    d[(l+j*64)*2+1] = ((u32)f2bf(v.w)<<16) | f2bf(v.z);
  }
  #pragma unroll
  for (int o=32;o;o>>=1) ss += __shfl_down(ss,o);
  if (l==0) nrm2[r]=ss;
}

__global__ __launch_bounds__(256) void prep_query(const float* __restrict__ src, u16* __restrict__ qb,
                                                  float* __restrict__ q2, u16* __restrict__ comb){
  int r = blockIdx.x*4 + (threadIdx.x>>6);
  int l = threadIdx.x & 63;
  const float4* s4 = (const float4*)(src + (long)r*ND);
  u32* dq = (u32*)(qb + (long)r*ND);
  u32* dc = (u32*)(comb + (long)r*2*ND);
  float ss = 0.f;
  #pragma unroll
  for (int j=0;j<3;j++){
    float4 v = s4[l + j*64];
    ss += v.x*v.x + v.y*v.y + v.z*v.z + v.w*v.w;
    u32 p0 = ((u32)f2bf(v.y)<<16) | f2bf(v.x);
    u32 p1 = ((u32)f2bf(v.w)<<16) | f2bf(v.z);
    dq[(l+j*64)*2]=p0; dq[(l+j*64)*2+1]=p1;
    dc[(l+j*64)*2]=p0; dc[(l+j*64)*2+1]=p1;
  }
  #pragma unroll
  for (int o=32;o;o>>=1) ss += __shfl_down(ss,o);
  if (l==0) q2[r]=ss;
}

__global__ void cvt_bf(const float* __restrict__ s, u16* __restrict__ d, int n){
  int i = blockIdx.x*256 + threadIdx.x;
  if (i<n) d[i] = f2bf(s[i]);
}

// wkt[h][d][hd] = Wk[h*96+hd][d]
__global__ void transpose_wk(const float* __restrict__ Wk, u16* __restrict__ wkt){
  int i = blockIdx.x*256 + threadIdx.x;
  if (i >= NH*ND*96) return;
  int h = i / (ND*96); int rem = i % (ND*96); int d = rem / 96; int hd = rem % 96;
  wkt[i] = f2bf(Wk[(long)(h*96+hd)*ND + d]);
}

// ---------------- bf16 A@B^T MFMA GEMM, 128x128x32 tile, 4 waves ----------------
// Double-buffered LDS + 1-deep global_load_lds prefetch with counted vmcnt(4) and
// raw s_barrier (no __syncthreads: it would drain vmcnt to 0 and kill the pipeline).
// MODE 0: C f32 = relu(acc + bias)         (gate hidden)
// MODE 1: C bf16 = acc + bias              (qp / u / ctx2)
// MODE 2: C f32 = d2 = q2[r]+m2[c]-2acc    (sample distances)
// MODE 3: candidate filter: d2 <= thr[r] -> atomic append
// MODE 4: ctx = acc + bias; out2 = bf16(ctx); Cf f32 = qsrc + ctx  (Wo epilogue)
template<int MODE>
__global__ __launch_bounds__(256)
void gemm_bt(const u16* __restrict__ A, int lda, long az,
             const u16* __restrict__ Bm, int ldb, long bz,
             int Ndim, int Kdim,
             float* __restrict__ Cf, u16* __restrict__ Cb, int ldc, long cz,
             const float* __restrict__ bias, long biasz,
             const float* __restrict__ q2, const float* __restrict__ m2, const float* __restrict__ thr,
             float* __restrict__ cand_d2, int* __restrict__ cand_idx, int* __restrict__ cnt,
             const float* __restrict__ qsrc, u16* __restrict__ out2, int ldo2)
{
  const int t = threadIdx.x;
  const int lane = t & 63, wid = t >> 6;
  const int m0 = blockIdx.x*128, n0 = blockIdx.y*128, z = blockIdx.z;
  A += (long)z*az; Bm += (long)z*bz;
  __shared__ u16 As[2][128*32], Bs[2][128*32];
  f32x4 acc[4][4];
  #pragma unroll
  for (int m=0;m<4;m++)
    #pragma unroll
    for (int n=0;n<4;n++) acc[m][n] = f32x4{0.f,0.f,0.f,0.f};

  const int wr = (wid>>1)*64, wc = (wid&1)*64;

  // global_load_lds: LDS dest is linear base+lane*16; pre-swizzle the SOURCE k-chunk so
  // LDS[row][slot] holds k-chunk (slot ^ ((row>>1)&3)) — matching the frag-read XOR below.
  const int c0 = wid*2, c1 = wid*2+1;
  const int ra0 = c0*16 + (lane>>2), ra1 = c1*16 + (lane>>2);
  const int g0 = (lane&3) ^ ((ra0>>1)&3), g1 = (lane&3) ^ ((ra1>>1)&3);
  const u16* a0 = &A[(long)(m0+ra0)*lda + g0*8];
  const u16* a1 = &A[(long)(m0+ra1)*lda + g1*8];
  int jb0 = n0+ra0; if (jb0>=Ndim) jb0=Ndim-1;
  int jb1 = n0+ra1; if (jb1>=Ndim) jb1=Ndim-1;
  const u16* b0 = &Bm[(long)jb0*ldb + g0*8];
  const u16* b1 = &Bm[(long)jb1*ldb + g1*8];

  auto stage = [&](int k0, int buf){
    gload_lds16(a0 + k0, &As[buf][c0*512]);
    gload_lds16(a1 + k0, &As[buf][c1*512]);
    gload_lds16(b0 + k0, &Bs[buf][c0*512]);
    gload_lds16(b1 + k0, &Bs[buf][c1*512]);
  };

  const int nt = Kdim >> 5;
  stage(0, 0);
  #pragma unroll 1
  for (int ti=0; ti<nt; ++ti){
    const int cur = ti & 1;
    if (ti+1 < nt){
      stage((ti+1)*32, cur^1);
      asm volatile("s_waitcnt vmcnt(4)" ::: "memory");   // tile ti's 4 oldest DMAs done
    } else {
      asm volatile("s_waitcnt vmcnt(0)" ::: "memory");
    }
    __builtin_amdgcn_s_barrier();
    const u16* Ab = As[cur];
    const u16* Bb = Bs[cur];
    bf16x8 af[4], bfr[4];
    #pragma unroll
    for (int m=0;m<4;m++){
      int row = wr + m*16 + (lane&15);
      int slot = ((lane>>4) ^ ((row>>1)&3));
      af[m] = __builtin_bit_cast(bf16x8, *(const uint4*)&Ab[row*32 + slot*8]);
    }
    #pragma unroll
    for (int n=0;n<4;n++){
      int row = wc + n*16 + (lane&15);
      int slot = ((lane>>4) ^ ((row>>1)&3));
      bfr[n] = __builtin_bit_cast(bf16x8, *(const uint4*)&Bb[row*32 + slot*8]);
    }
    #pragma unroll
    for (int m=0;m<4;m++)
      #pragma unroll
      for (int n=0;n<4;n++)
        acc[m][n] = __builtin_amdgcn_mfma_f32_16x16x32_bf16(af[m], bfr[n], acc[m][n], 0,0,0);
    __builtin_amdgcn_s_barrier();   // all waves' frag reads complete (lgkm-enforced) before overwrite
  }

  const float* bz_p = ((MODE==0)||(MODE==1)||(MODE==4)) && bias ? bias + (long)z*biasz : nullptr;
  #pragma unroll
  for (int m=0;m<4;m++){
    #pragma unroll
    for (int n=0;n<4;n++){
      #pragma unroll
      for (int q=0;q<4;q++){
        int r = m0 + wr + m*16 + ((lane>>4)<<2) + q;
        int c = n0 + wc + n*16 + (lane&15);
        float v = acc[m][n][q];
        if (MODE==0){
          if (c<Ndim){ if(bz_p) v += bz_p[c]; Cf[(long)r*ldc + (long)z*cz + c] = fmaxf(v,0.f); }
        } else if (MODE==1){
          if (c<Ndim){ if(bz_p) v += bz_p[c]; Cb[(long)r*ldc + (long)z*cz + c] = f2bf(v); }
        } else if (MODE==2){
          if (c<Ndim){ float d2 = fmaxf(q2[r]+m2[c]-2.f*v, 0.f); Cf[(long)r*ldc + c] = d2; }
        } else if (MODE==3){
          if (c<Ndim){
            float d2 = fmaxf(q2[r]+m2[c]-2.f*v, 0.f);
            if (d2 <= thr[r]){
              int p = atomicAdd(&cnt[r],1);
              if (p < CAP){ cand_d2[(long)r*CAP+p]=d2; cand_idx[(long)r*CAP+p]=c; }
            }
          }
        } else {
          if (c<Ndim){
            float ctx = v + (bz_p?bz_p[c]:0.f);
            out2[(long)r*ldo2 + c] = f2bf(ctx);
            Cf[(long)r*ldc + c] = qsrc[(long)r*ND+c] + ctx;   // enhanced, f32
          }
        }
      }
    }
  }
}

// ---------------- per-query threshold: per-wave bisection for 25th-smallest, min over waves ----------------
__global__ __launch_bounds__(256) void find_thr(const float* __restrict__ d2s, float* __restrict__ thr){
  int b = blockIdx.x, w = threadIdx.x>>6, l = threadIdx.x&63;
  const float4* base = (const float4*)(d2s + (long)b*SAMP + w*1024);
  float v[16];
  #pragma unroll
  for (int j=0;j<4;j++){
    float4 q = base[l*4+j];
    v[j*4]=q.x; v[j*4+1]=q.y; v[j*4+2]=q.z; v[j*4+3]=q.w;
  }
  u32 lo=0, hi=0x7f7fffffu;
  for (int it=0; it<28; ++it){
    u32 mid = (lo+hi)>>1;
    float fm = __builtin_bit_cast(float, mid);
    int c=0;
    #pragma unroll
    for (int j=0;j<16;j++) c += (v[j] <= fm) ? 1 : 0;
    #pragma unroll
    for (int o=32;o;o>>=1) c += __shfl_down(c,o);
    c = __shfl(c,0);
    if (c >= RSEL) hi = mid; else lo = mid+1;
  }
  __shared__ float wt[4];
  if (l==0) wt[w] = __builtin_bit_cast(float, hi);
  __syncthreads();
  if (threadIdx.x==0) thr[b] = fminf(fminf(wt[0],wt[1]), fminf(wt[2],wt[3]));
}

// ---------------- exact top-50: parallel rank-count over candidates ----------------
__global__ __launch_bounds__(256) void select50(const float* __restrict__ cand_d2, const int* __restrict__ cand_idx,
                                                const int* __restrict__ cnt, int* __restrict__ sel,
                                                float* __restrict__ dists, float* __restrict__ dsum){
  int b = blockIdx.x, t = threadIdx.x;
  __shared__ u64 arr[CAP];
  __shared__ float dS[NK];
  int n = cnt[b]; if (n > CAP) n = CAP;
  for (int i=t;i<n;i+=256){
    float d2 = fmaxf(cand_d2[(long)b*CAP+i],0.f);
    arr[i] = ((u64)__builtin_bit_cast(u32, d2)<<32) | (u32)cand_idx[(long)b*CAP+i];
  }
  if (t < NK){ dS[t]=0.f; sel[b*NK+t]=0; dists[b*NK+t]=0.f; }  // safety init (n<50 ~impossible)
  __syncthreads();
  for (int i=t;i<n;i+=256){
    u64 me = arr[i];
    int rank = 0;
    for (int j=0;j<n;j++) rank += (arr[j] < me) ? 1 : 0;   // unique keys -> unique ranks
    if (rank < NK){
      float d = sqrtf(__builtin_bit_cast(float, (u32)(me>>32)));
      sel[b*NK+rank] = (int)(u32)(me & 0xffffffffu);
      dists[b*NK+rank] = d;
      dS[rank] = d;
    }
  }
  __syncthreads();
  if (t==0){ float s=0.f; for (int r=0;r<NK;r++) s+=dS[r]; dsum[b]=s; }
}

__global__ void mean_kernel(const float* __restrict__ dsum, float* __restrict__ meanbuf){
  int t = threadIdx.x;
  float s=0.f; for (int i=t;i<NB;i+=256) s += dsum[i];
  __shared__ float red[256];
  red[t]=s; __syncthreads();
  #pragma unroll
  for (int st=128;st>0;st>>=1){ if(t<st) red[t]+=red[t+st]; __syncthreads(); }
  if (t==0){ float mean = red[0]/(float)(NB*NK); meanbuf[0]=mean; meanbuf[1]=1.f/mean; }
}

// ---------------- per-query attention: online softmax, bf16 gathers, + rag ----------------
__global__ __launch_bounds__(256) void attn_kernel(
    const int* __restrict__ sel, const u16* __restrict__ mkb,
    const u16* __restrict__ ub, const float* __restrict__ dists,
    const float* __restrict__ mvals, const float* __restrict__ meanbuf,
    u16* __restrict__ sb, float* __restrict__ out_rag)
{
  const int b = blockIdx.x, t = threadIdx.x;
  __shared__ u16 nkS[25*772];
  __shared__ u16 uS[8*772];
  __shared__ float sc[NH*32];
  __shared__ float mh[NH], dh[NH], scS[NH];
  __shared__ int selS[NK];
  if (t < NK) selS[t] = sel[b*NK+t];
  if (t >= 64 && t < 64+NH){ mh[t-64] = -1e30f; dh[t-64] = 0.f; }
  {
    const u32* src = (const u32*)&ub[(long)b*NH*ND];
    for (int i=t;i<NH*(ND/2);i+=256){
      int h = i/(ND/2), d = i%(ND/2);
      ((u32*)&uS[h*772])[d] = src[h*(ND/2)+d];
    }
  }
  float sacc[3][NH];
  #pragma unroll
  for (int j=0;j<3;j++)
    #pragma unroll
    for (int h=0;h<NH;h++) sacc[j][h]=0.f;
  const float rs = 0.10206207261596575f;  // 1/sqrt(96)

  for (int half=0; half<2; ++half){
    __syncthreads();
    for (int k=0;k<25;k++){
      const u32* src = (const u32*)&mkb[(long)selS[half*25+k]*ND];
      u32* dst = (u32*)&nkS[k*772];
      for (int i=t;i<ND/2;i+=256) dst[i] = src[i];
    }
    __syncthreads();
    if (t < 200){
      const u32* nr = (const u32*)&nkS[(t%25)*772];
      const u32* ur = (const u32*)&uS[(t/25)*772];
      float acc = 0.f;
      #pragma unroll 8
      for (int d=0; d<ND/2; d++){
        u32 a = nr[d], uu = ur[d];
        acc += bf2f((u16)a)*bf2f((u16)uu) + bf2f((u16)(a>>16))*bf2f((u16)(uu>>16));
      }
      sc[(t/25)*32 + (t%25)] = acc*rs;
    }
    __syncthreads();
    if (t < NH){
      float mn = mh[t];
      #pragma unroll
      for (int k=0;k<25;k++) mn = fmaxf(mn, sc[t*32+k]);
      float scale = __expf(mh[t]-mn);
      float d = dh[t]*scale;
      #pragma unroll
      for (int k=0;k<25;k++){ float e = __expf(sc[t*32+k]-mn); sc[t*32+k]=e; d+=e; }
      mh[t]=mn; dh[t]=d; scS[t]=scale;
    }
    __syncthreads();
    #pragma unroll
    for (int j=0;j<3;j++){
      int dd = t + j*256;
      #pragma unroll
      for (int h=0;h<NH;h++) sacc[j][h] *= scS[h];
      for (int k=0;k<25;k++){
        float nv = bf2f(nkS[k*772+dd]);
        float w0,w1,w2,w3,w4,w5,w6,w7;
        w0=sc[0*32+k]; w1=sc[1*32+k]; w2=sc[2*32+k]; w3=sc[3*32+k];
        w4=sc[4*32+k]; w5=sc[5*32+k]; w6=sc[6*32+k]; w7=sc[7*32+k];
        sacc[j][0]+=w0*nv; sacc[j][1]+=w1*nv; sacc[j][2]+=w2*nv; sacc[j][3]+=w3*nv;
        sacc[j][4]+=w4*nv; sacc[j][5]+=w5*nv; sacc[j][6]+=w6*nv; sacc[j][7]+=w7*nv;
      }
    }
  }
  float inv[NH];
  #pragma unroll
  for (int h=0;h<NH;h++) inv[h] = 1.f/dh[h];
  #pragma unroll
  for (int j=0;j<3;j++){
    int dd = t + j*256;
    #pragma unroll
    for (int h=0;h<NH;h++) sb[(long)b*NH*ND + h*ND + dd] = f2bf(sacc[j][h]*inv[h]);
  }
  if (t < 64){
    float num=0.f, den=0.f;
    if (t < NK){
      float d = dists[b*NK+t];
      float v = mvals[selS[t]];
      float e = __expf(-d*meanbuf[1]);
      num = e*v; den = e;
    }
    #pragma unroll
    for (int o=32;o;o>>=1){ num += __shfl_down(num,o); den += __shfl_down(den,o); }
    if (t==0) out_rag[b] = num/den;
  }
}

// ---------------- gate output ----------------
__global__ void gate2_kernel(const float* __restrict__ hg, const float* __restrict__ Wg2,
                             const float* __restrict__ bg2, float* __restrict__ outg){
  int b = blockIdx.x*4 + (threadIdx.x>>6);
  int l = threadIdx.x & 63;
  float s=0.f;
  for (int i=l;i<256;i+=64) s += hg[(long)b*256+i]*Wg2[i];
  #pragma unroll
  for (int o=32;o;o>>=1) s += __shfl_down(s,o);
  if (l==0) outg[b] = 1.f/(1.f+__expf(-(s+bg2[0])));
}

extern "C" void kernel_launch(void* const* d_in, const int* in_sizes, int n_in,
                              void* d_out, int out_size, void* d_ws, size_t ws_size,
                              hipStream_t stream){
  const float* query = (const float*)d_in[0];
  const float* mkeys = (const float*)d_in[1];
  const float* mvals = (const float*)d_in[2];
  const float* Wq  = (const float*)d_in[3];
  const float* bq  = (const float*)d_in[4];
  const float* Wk  = (const float*)d_in[5];
  const float* Wv  = (const float*)d_in[7];
  const float* bv  = (const float*)d_in[8];
  const float* Wo  = (const float*)d_in[9];
  const float* bo  = (const float*)d_in[10];
  const float* Wg1 = (const float*)d_in[11];
  const float* bg1 = (const float*)d_in[12];
  const float* Wg2 = (const float*)d_in[13];
  const float* bg2 = (const float*)d_in[14];
  float* out = (float*)d_out;           // f32: [enhanced B*768 | rag B | gate B]

  char* ws = (char*)d_ws;
  size_t off = 0;
  auto alloc = [&](size_t bytes)->char*{ char* p = ws + off; off += (bytes + 255) & ~(size_t)255; return p; };

  u16*   mkb   = (u16*)  alloc((size_t)NM*ND*2);
  u16*   qb    = (u16*)  alloc((size_t)NB*ND*2);
  u16*   comb  = (u16*)  alloc((size_t)NB*2*ND*2);
  float* q2    = (float*)alloc(NB*4);
  float* m2    = (float*)alloc(NM*4);
  u16*   wqb   = (u16*)  alloc((size_t)ND*ND*2);
  u16*   wkt   = (u16*)  alloc((size_t)ND*ND*2);
  u16*   wvb   = (u16*)  alloc((size_t)ND*ND*2);
  u16*   wob   = (u16*)  alloc((size_t)ND*ND*2);
  u16*   wg1b  = (u16*)  alloc((size_t)256*2*ND*2);
  float* d2s   = (float*)alloc((size_t)NB*SAMP*4);   // aliased below by cand arrays (d2s dead after find_thr)
  float* thr   = (float*)alloc(NB*4);
  int*   cnt   = (int*)  alloc(NB*4);
  int*   sel   = (int*)  alloc((size_t)NB*NK*4);
  float* dists = (float*)alloc((size_t)NB*NK*4);
  float* dsum  = (float*)alloc(NB*4);
  float* meanbuf=(float*)alloc(256);
  u16*   qpb   = (u16*)  alloc((size_t)NB*ND*2);
  u16*   ubuf  = (u16*)  alloc((size_t)NB*NH*ND*2);
  u16*   sbuf  = (u16*)  alloc((size_t)NB*NH*ND*2);
  u16*   ctx2b = (u16*)  alloc((size_t)NB*ND*2);
  float* hg    = (float*)alloc((size_t)NB*256*4);
  // alias: cand buffers live in d2s region (16.8MB; cand needs 8.4+8.4MB); stream-ordered safe
  float* cand_d2 = d2s;
  int*   cand_idx= (int*)(d2s + (size_t)NB*CAP);
  (void)ws_size; (void)in_sizes; (void)n_in; (void)out_size;

  // prep
  prep_query<<<NB/4, 256, 0, stream>>>(query, qb, q2, comb);
  prep_mk<<<NM/4, 256, 0, stream>>>(mkeys, mkb, m2);
  cvt_bf<<<(ND*ND+255)/256, 256, 0, stream>>>(Wq, wqb, ND*ND);
  cvt_bf<<<(ND*ND+255)/256, 256, 0, stream>>>(Wv, wvb, ND*ND);
  cvt_bf<<<(ND*ND+255)/256, 256, 0, stream>>>(Wo, wob, ND*ND);
  cvt_bf<<<(256*2*ND+255)/256, 256, 0, stream>>>(Wg1, wg1b, 256*2*ND);
  transpose_wk<<<(ND*ND+255)/256, 256, 0, stream>>>(Wk, wkt);

  // retrieval: sample -> threshold -> filtered candidates -> exact top-50
  gemm_bt<2><<<dim3(NB/128, SAMP/128, 1), 256, 0, stream>>>(qb,ND,0, mkb,ND,0, SAMP,ND,
      d2s,nullptr,SAMP,0, nullptr,0, q2,m2,nullptr, nullptr,nullptr,nullptr, nullptr,nullptr,0);
  find_thr<<<NB, 256, 0, stream>>>(d2s, thr);
  hipMemsetAsync(cnt, 0, NB*sizeof(int), stream);
  gemm_bt<3><<<dim3(NB/128, (NM+127)/128, 1), 256, 0, stream>>>(qb,ND,0, mkb,ND,0, NM,ND,
      nullptr,nullptr,0,0, nullptr,0, q2,m2,thr, cand_d2,cand_idx,cnt, nullptr,nullptr,0);
  select50<<<NB, 256, 0, stream>>>(cand_d2, cand_idx, cnt, sel, dists, dsum);
  mean_kernel<<<1, 256, 0, stream>>>(dsum, meanbuf);

  // q-projection, then u[b,h,:] = Wk_h^T @ q_h  (collapses K-projection)
  gemm_bt<1><<<dim3(NB/128, ND/128, 1), 256, 0, stream>>>(qb,ND,0, wqb,ND,0, ND,ND,
      nullptr,qpb,ND,0, bq,0, nullptr,nullptr,nullptr, nullptr,nullptr,nullptr, nullptr,nullptr,0);
  gemm_bt<1><<<dim3(NB/128, ND/128, NH), 256, 0, stream>>>(qpb,ND,96, wkt,96,(long)ND*96, ND,96,
      nullptr,ubuf,NH*ND,ND, nullptr,0, nullptr,nullptr,nullptr, nullptr,nullptr,nullptr, nullptr,nullptr,0);

  // attention scores/softmax/weighted-neighbor-sum + rag prediction
  attn_kernel<<<NB, 256, 0, stream>>>(sel, mkb, ubuf, dists, mvals, meanbuf, sbuf, out + (size_t)NB*ND);

  // ctx2[b,h*96+hd] = Wv_h @ s_h + bv   (collapses V-projection; exact since sum(attn)=1)
  gemm_bt<1><<<dim3(NB/128, 1, NH), 256, 0, stream>>>(sbuf,NH*ND,ND, wvb,ND,(long)96*ND, 96,ND,
      nullptr,ctx2b,ND,96, bv,96, nullptr,nullptr,nullptr, nullptr,nullptr,nullptr, nullptr,nullptr,0);

  // context = ctx2 @ Wo^T + bo; enhanced (f32) = query + context -> out; context -> combined[:,768:]
  gemm_bt<4><<<dim3(NB/128, ND/128, 1), 256, 0, stream>>>(ctx2b,ND,0, wob,ND,0, ND,ND,
      out,nullptr,ND,0, bo,0, nullptr,nullptr,nullptr, nullptr,nullptr,nullptr, query, comb+ND, 2*ND);

  // gate MLP
  gemm_bt<0><<<dim3(NB/128, 2, 1), 256, 0, stream>>>(comb,2*ND,0, wg1b,2*ND,0, 256,2*ND,
      hg,nullptr,256,0, bg1,0, nullptr,nullptr,nullptr, nullptr,nullptr,nullptr, nullptr,nullptr,0);
  gate2_kernel<<<NB/4, 256, 0, stream>>>(hg, Wg2, bg2, out + (size_t)NB*ND + NB);
}

// Round 5
// 881.447 us; speedup vs baseline: 1.3249x; 1.3249x over previous
//
#include <hip/hip_runtime.h>

typedef unsigned int u32;
typedef unsigned short u16;
typedef unsigned long long u64;
typedef __bf16 bf16x8 __attribute__((ext_vector_type(8)));
typedef float f32x4 __attribute__((ext_vector_type(4)));

#define DEVI __device__ __forceinline__

DEVI u16 f2bf(float x){ u32 u = __builtin_bit_cast(u32, x); return (u16)((u + 0x7fffu + ((u>>16)&1u)) >> 16); }
DEVI float bf2f(u16 h){ return __builtin_bit_cast(float, ((u32)h)<<16); }

DEVI void gload_lds16(const void* g, void* l){
  __builtin_amdgcn_global_load_lds((const __attribute__((address_space(1))) void*)g,
                                   (__attribute__((address_space(3))) void*)l, 16, 0, 0);
}

// constants
#define NB 1024
#define ND 768
#define NM 50000
#define NK 50
#define NH 8
#define SAMP 4096
#define RSEL 25
#define CAP 2048

// ---------------- prep: wave-per-row f32 -> bf16 + sumsq ----------------
__global__ __launch_bounds__(256) void prep_mk(const float* __restrict__ src, u16* __restrict__ dst,
                                               float* __restrict__ nrm2){
  int r = blockIdx.x*4 + (threadIdx.x>>6);
  int l = threadIdx.x & 63;
  const float4* s4 = (const float4*)(src + (long)r*ND);
  u32* d = (u32*)(dst + (long)r*ND);
  float ss = 0.f;
  #pragma unroll
  for (int j=0;j<3;j++){
    float4 v = s4[l + j*64];
    ss += v.x*v.x + v.y*v.y + v.z*v.z + v.w*v.w;
    d[(l+j*64)*2]   = ((u32)f2bf(v.y)<<16) | f2bf(v.x);
    d[(l+j*64)*2+1] = ((u32)f2bf(v.w)<<16) | f2bf(v.z);
  }
  #pragma unroll
  for (int o=32;o;o>>=1) ss += __shfl_down(ss,o);
  if (l==0) nrm2[r]=ss;
}

__global__ __launch_bounds__(256) void prep_query(const float* __restrict__ src, u16* __restrict__ qb,
                                                  float* __restrict__ q2, u16* __restrict__ comb){
  int r = blockIdx.x*4 + (threadIdx.x>>6);
  int l = threadIdx.x & 63;
  const float4* s4 = (const float4*)(src + (long)r*ND);
  u32* dq = (u32*)(qb + (long)r*ND);
  u32* dc = (u32*)(comb + (long)r*2*ND);
  float ss = 0.f;
  #pragma unroll
  for (int j=0;j<3;j++){
    float4 v = s4[l + j*64];
    ss += v.x*v.x + v.y*v.y + v.z*v.z + v.w*v.w;
    u32 p0 = ((u32)f2bf(v.y)<<16) | f2bf(v.x);
    u32 p1 = ((u32)f2bf(v.w)<<16) | f2bf(v.z);
    dq[(l+j*64)*2]=p0; dq[(l+j*64)*2+1]=p1;
    dc[(l+j*64)*2]=p0; dc[(l+j*64)*2+1]=p1;
  }
  #pragma unroll
  for (int o=32;o;o>>=1) ss += __shfl_down(ss,o);
  if (l==0) q2[r]=ss;
}

__global__ void cvt_bf(const float* __restrict__ s, u16* __restrict__ d, int n){
  int i = blockIdx.x*256 + threadIdx.x;
  if (i<n) d[i] = f2bf(s[i]);
}

// wkt[h][d][hd] = Wk[h*96+hd][d]
__global__ void transpose_wk(const float* __restrict__ Wk, u16* __restrict__ wkt){
  int i = blockIdx.x*256 + threadIdx.x;
  if (i >= NH*ND*96) return;
  int h = i / (ND*96); int rem = i % (ND*96); int d = rem / 96; int hd = rem % 96;
  wkt[i] = f2bf(Wk[(long)(h*96+hd)*ND + d]);
}

// ============ reg-staged 128x128x32 GEMM (r2 structure) for the two big retrieval GEMMs ============
// 1-D grid, XCD-aware decode: all 8 M-tiles of an N-panel get bid ≡ y (mod 8) -> same XCD,
// temporally adjacent -> panel fetched once per XCD L2 instead of 8x.
// MODE 2: C f32 = d2 = q2[r]+m2[c]-2acc   (sample distances)
// MODE 3: candidate filter: d2 <= thr[r] -> atomic append
template<int MODE>
__global__ __launch_bounds__(256)
void gemm_rs(const u16* __restrict__ A, int lda,
             const u16* __restrict__ Bm, int ldb,
             int Ndim, int Kdim, int ny,
             float* __restrict__ Cf, int ldc,
             const float* __restrict__ q2, const float* __restrict__ m2, const float* __restrict__ thr,
             float* __restrict__ cand_d2, int* __restrict__ cand_idx, int* __restrict__ cnt)
{
  const int cxcd = blockIdx.x & 7, j = blockIdx.x >> 3;
  const int xt = j & 7, yhi = j >> 3;
  const int y = yhi*8 + cxcd;
  if (y >= ny) return;
  const int m0 = xt*128, n0 = y*128;

  const int t = threadIdx.x;
  const int lane = t & 63, wid = t >> 6;
  __shared__ u16 As[128*32], Bs[128*32];
  f32x4 acc[4][4];
  #pragma unroll
  for (int m=0;m<4;m++)
    #pragma unroll
    for (int n=0;n<4;n++) acc[m][n] = f32x4{0.f,0.f,0.f,0.f};

  const int wr = (wid>>1)*64, wc = (wid&1)*64;
  const int sr = t>>2, sc4 = t&3;

  for (int k0=0; k0<Kdim; k0+=32){
    __syncthreads();
    #pragma unroll
    for (int i=0;i<2;i++){
      int r = sr + i*64;
      int slot = (sc4 ^ ((r>>1)&3));              // XOR swizzle: 2-way (free) on frag reads
      uint4 av = *(const uint4*)&A[(long)(m0+r)*lda + k0 + sc4*8];
      *(uint4*)&As[r*32 + slot*8] = av;
      int jb = n0 + r; if (jb >= Ndim) jb = Ndim-1;
      uint4 bv = *(const uint4*)&Bm[(long)jb*ldb + k0 + sc4*8];
      *(uint4*)&Bs[r*32 + slot*8] = bv;
    }
    __syncthreads();
    bf16x8 af[4], bfr[4];
    #pragma unroll
    for (int m=0;m<4;m++){
      int row = wr + m*16 + (lane&15);
      int slot = ((lane>>4) ^ ((row>>1)&3));
      af[m] = __builtin_bit_cast(bf16x8, *(const uint4*)&As[row*32 + slot*8]);
    }
    #pragma unroll
    for (int n=0;n<4;n++){
      int row = wc + n*16 + (lane&15);
      int slot = ((lane>>4) ^ ((row>>1)&3));
      bfr[n] = __builtin_bit_cast(bf16x8, *(const uint4*)&Bs[row*32 + slot*8]);
    }
    #pragma unroll
    for (int m=0;m<4;m++)
      #pragma unroll
      for (int n=0;n<4;n++)
        acc[m][n] = __builtin_amdgcn_mfma_f32_16x16x32_bf16(af[m], bfr[n], acc[m][n], 0,0,0);
  }

  #pragma unroll
  for (int m=0;m<4;m++){
    #pragma unroll
    for (int n=0;n<4;n++){
      #pragma unroll
      for (int q=0;q<4;q++){
        int r = m0 + wr + m*16 + ((lane>>4)<<2) + q;
        int c = n0 + wc + n*16 + (lane&15);
        float v = acc[m][n][q];
        if (MODE==2){
          if (c<Ndim){ float d2 = fmaxf(q2[r]+m2[c]-2.f*v, 0.f); Cf[(long)r*ldc + c] = d2; }
        } else {
          if (c<Ndim){
            float d2 = fmaxf(q2[r]+m2[c]-2.f*v, 0.f);
            if (d2 <= thr[r]){
              int p = atomicAdd(&cnt[r],1);
              if (p < CAP){ cand_d2[(long)r*CAP+p]=d2; cand_idx[(long)r*CAP+p]=c; }
            }
          }
        }
      }
    }
  }
}

// ============ DMA double-buffered GEMM (r4 structure) for the small projection GEMMs ============
// MODE 0: C f32 = relu(acc + bias)         (gate hidden)
// MODE 1: C bf16 = acc + bias              (qp / u / ctx2)
// MODE 4: ctx = acc + bias; out2 = bf16(ctx); Cf f32 = qsrc + ctx  (Wo epilogue)
template<int MODE>
__global__ __launch_bounds__(256)
void gemm_dma(const u16* __restrict__ A, int lda, long az,
              const u16* __restrict__ Bm, int ldb, long bz,
              int Ndim, int Kdim,
              float* __restrict__ Cf, u16* __restrict__ Cb, int ldc, long cz,
              const float* __restrict__ bias, long biasz,
              const float* __restrict__ qsrc, u16* __restrict__ out2, int ldo2)
{
  const int t = threadIdx.x;
  const int lane = t & 63, wid = t >> 6;
  const int m0 = blockIdx.x*128, n0 = blockIdx.y*128, z = blockIdx.z;
  A += (long)z*az; Bm += (long)z*bz;
  __shared__ u16 As[2][128*32], Bs[2][128*32];
  f32x4 acc[4][4];
  #pragma unroll
  for (int m=0;m<4;m++)
    #pragma unroll
    for (int n=0;n<4;n++) acc[m][n] = f32x4{0.f,0.f,0.f,0.f};

  const int wr = (wid>>1)*64, wc = (wid&1)*64;

  const int c0 = wid*2, c1 = wid*2+1;
  const int ra0 = c0*16 + (lane>>2), ra1 = c1*16 + (lane>>2);
  const int g0 = (lane&3) ^ ((ra0>>1)&3), g1 = (lane&3) ^ ((ra1>>1)&3);
  const u16* a0 = &A[(long)(m0+ra0)*lda + g0*8];
  const u16* a1 = &A[(long)(m0+ra1)*lda + g1*8];
  int jb0 = n0+ra0; if (jb0>=Ndim) jb0=Ndim-1;
  int jb1 = n0+ra1; if (jb1>=Ndim) jb1=Ndim-1;
  const u16* b0 = &Bm[(long)jb0*ldb + g0*8];
  const u16* b1 = &Bm[(long)jb1*ldb + g1*8];

  auto stage = [&](int k0, int buf){
    gload_lds16(a0 + k0, &As[buf][c0*512]);
    gload_lds16(a1 + k0, &As[buf][c1*512]);
    gload_lds16(b0 + k0, &Bs[buf][c0*512]);
    gload_lds16(b1 + k0, &Bs[buf][c1*512]);
  };

  const int nt = Kdim >> 5;
  stage(0, 0);
  #pragma unroll 1
  for (int ti=0; ti<nt; ++ti){
    const int cur = ti & 1;
    if (ti+1 < nt){
      stage((ti+1)*32, cur^1);
      asm volatile("s_waitcnt vmcnt(4)" ::: "memory");
    } else {
      asm volatile("s_waitcnt vmcnt(0)" ::: "memory");
    }
    __builtin_amdgcn_s_barrier();
    const u16* Ab = As[cur];
    const u16* Bb = Bs[cur];
    bf16x8 af[4], bfr[4];
    #pragma unroll
    for (int m=0;m<4;m++){
      int row = wr + m*16 + (lane&15);
      int slot = ((lane>>4) ^ ((row>>1)&3));
      af[m] = __builtin_bit_cast(bf16x8, *(const uint4*)&Ab[row*32 + slot*8]);
    }
    #pragma unroll
    for (int n=0;n<4;n++){
      int row = wc + n*16 + (lane&15);
      int slot = ((lane>>4) ^ ((row>>1)&3));
      bfr[n] = __builtin_bit_cast(bf16x8, *(const uint4*)&Bb[row*32 + slot*8]);
    }
    #pragma unroll
    for (int m=0;m<4;m++)
      #pragma unroll
      for (int n=0;n<4;n++)
        acc[m][n] = __builtin_amdgcn_mfma_f32_16x16x32_bf16(af[m], bfr[n], acc[m][n], 0,0,0);
    __builtin_amdgcn_s_barrier();
  }

  const float* bz_p = bias ? bias + (long)z*biasz : nullptr;
  #pragma unroll
  for (int m=0;m<4;m++){
    #pragma unroll
    for (int n=0;n<4;n++){
      #pragma unroll
      for (int q=0;q<4;q++){
        int r = m0 + wr + m*16 + ((lane>>4)<<2) + q;
        int c = n0 + wc + n*16 + (lane&15);
        float v = acc[m][n][q];
        if (MODE==0){
          if (c<Ndim){ if(bz_p) v += bz_p[c]; Cf[(long)r*ldc + (long)z*cz + c] = fmaxf(v,0.f); }
        } else if (MODE==1){
          if (c<Ndim){ if(bz_p) v += bz_p[c]; Cb[(long)r*ldc + (long)z*cz + c] = f2bf(v); }
        } else {
          if (c<Ndim){
            float ctx = v + (bz_p?bz_p[c]:0.f);
            out2[(long)r*ldo2 + c] = f2bf(ctx);
            Cf[(long)r*ldc + c] = qsrc[(long)r*ND+c] + ctx;   // enhanced, f32
          }
        }
      }
    }
  }
}

// ---------------- per-query threshold: per-wave bisection for 25th-smallest, min over waves ----------------
__global__ __launch_bounds__(256) void find_thr(const float* __restrict__ d2s, float* __restrict__ thr){
  int b = blockIdx.x, w = threadIdx.x>>6, l = threadIdx.x&63;
  const float4* base = (const float4*)(d2s + (long)b*SAMP + w*1024);
  float v[16];
  #pragma unroll
  for (int j=0;j<4;j++){
    float4 q = base[l*4+j];
    v[j*4]=q.x; v[j*4+1]=q.y; v[j*4+2]=q.z; v[j*4+3]=q.w;
  }
  u32 lo=0, hi=0x7f7fffffu;
  for (int it=0; it<28; ++it){
    u32 mid = (lo+hi)>>1;
    float fm = __builtin_bit_cast(float, mid);
    int c=0;
    #pragma unroll
    for (int j=0;j<16;j++) c += (v[j] <= fm) ? 1 : 0;
    #pragma unroll
    for (int o=32;o;o>>=1) c += __shfl_down(c,o);
    c = __shfl(c,0);
    if (c >= RSEL) hi = mid; else lo = mid+1;
  }
  __shared__ float wt[4];
  if (l==0) wt[w] = __builtin_bit_cast(float, hi);
  __syncthreads();
  if (threadIdx.x==0) thr[b] = fminf(fminf(wt[0],wt[1]), fminf(wt[2],wt[3]));
}

// ---------------- exact top-50: parallel rank-count over candidates ----------------
__global__ __launch_bounds__(256) void select50(const float* __restrict__ cand_d2, const int* __restrict__ cand_idx,
                                                const int* __restrict__ cnt, int* __restrict__ sel,
                                                float* __restrict__ dists, float* __restrict__ dsum){
  int b = blockIdx.x, t = threadIdx.x;
  __shared__ u64 arr[CAP];
  __shared__ float dS[NK];
  int n = cnt[b]; if (n > CAP) n = CAP;
  for (int i=t;i<n;i+=256){
    float d2 = fmaxf(cand_d2[(long)b*CAP+i],0.f);
    arr[i] = ((u64)__builtin_bit_cast(u32, d2)<<32) | (u32)cand_idx[(long)b*CAP+i];
  }
  if (t < NK){ dS[t]=0.f; sel[b*NK+t]=0; dists[b*NK+t]=0.f; }  // safety init (n<50 ~impossible)
  __syncthreads();
  for (int i=t;i<n;i+=256){
    u64 me = arr[i];
    int rank = 0;
    for (int j=0;j<n;j++) rank += (arr[j] < me) ? 1 : 0;   // unique keys -> unique ranks
    if (rank < NK){
      float d = sqrtf(__builtin_bit_cast(float, (u32)(me>>32)));
      sel[b*NK+rank] = (int)(u32)(me & 0xffffffffu);
      dists[b*NK+rank] = d;
      dS[rank] = d;
    }
  }
  __syncthreads();
  if (t==0){ float s=0.f; for (int r=0;r<NK;r++) s+=dS[r]; dsum[b]=s; }
}

__global__ void mean_kernel(const float* __restrict__ dsum, float* __restrict__ meanbuf){
  int t = threadIdx.x;
  float s=0.f; for (int i=t;i<NB;i+=256) s += dsum[i];
  __shared__ float red[256];
  red[t]=s; __syncthreads();
  #pragma unroll
  for (int st=128;st>0;st>>=1){ if(t<st) red[t]+=red[t+st]; __syncthreads(); }
  if (t==0){ float mean = red[0]/(float)(NB*NK); meanbuf[0]=mean; meanbuf[1]=1.f/mean; }
}

// ---------------- per-query attention: online softmax, bf16 gathers, + rag ----------------
__global__ __launch_bounds__(256) void attn_kernel(
    const int* __restrict__ sel, const u16* __restrict__ mkb,
    const u16* __restrict__ ub, const float* __restrict__ dists,
    const float* __restrict__ mvals, const float* __restrict__ meanbuf,
    u16* __restrict__ sb, float* __restrict__ out_rag)
{
  const int b = blockIdx.x, t = threadIdx.x;
  __shared__ u16 nkS[25*772];
  __shared__ u16 uS[8*772];
  __shared__ float sc[NH*32];
  __shared__ float mh[NH], dh[NH], scS[NH];
  __shared__ int selS[NK];
  if (t < NK) selS[t] = sel[b*NK+t];
  if (t >= 64 && t < 64+NH){ mh[t-64] = -1e30f; dh[t-64] = 0.f; }
  {
    const u32* src = (const u32*)&ub[(long)b*NH*ND];
    for (int i=t;i<NH*(ND/2);i+=256){
      int h = i/(ND/2), d = i%(ND/2);
      ((u32*)&uS[h*772])[d] = src[h*(ND/2)+d];
    }
  }
  float sacc[3][NH];
  #pragma unroll
  for (int j=0;j<3;j++)
    #pragma unroll
    for (int h=0;h<NH;h++) sacc[j][h]=0.f;
  const float rs = 0.10206207261596575f;  // 1/sqrt(96)

  for (int half=0; half<2; ++half){
    __syncthreads();
    for (int k=0;k<25;k++){
      const u32* src = (const u32*)&mkb[(long)selS[half*25+k]*ND];
      u32* dst = (u32*)&nkS[k*772];
      for (int i=t;i<ND/2;i+=256) dst[i] = src[i];
    }
    __syncthreads();
    if (t < 200){
      const u32* nr = (const u32*)&nkS[(t%25)*772];
      const u32* ur = (const u32*)&uS[(t/25)*772];
      float acc = 0.f;
      #pragma unroll 8
      for (int d=0; d<ND/2; d++){
        u32 a = nr[d], uu = ur[d];
        acc += bf2f((u16)a)*bf2f((u16)uu) + bf2f((u16)(a>>16))*bf2f((u16)(uu>>16));
      }
      sc[(t/25)*32 + (t%25)] = acc*rs;
    }
    __syncthreads();
    if (t < NH){
      float mn = mh[t];
      #pragma unroll
      for (int k=0;k<25;k++) mn = fmaxf(mn, sc[t*32+k]);
      float scale = __expf(mh[t]-mn);
      float d = dh[t]*scale;
      #pragma unroll
      for (int k=0;k<25;k++){ float e = __expf(sc[t*32+k]-mn); sc[t*32+k]=e; d+=e; }
      mh[t]=mn; dh[t]=d; scS[t]=scale;
    }
    __syncthreads();
    #pragma unroll
    for (int j=0;j<3;j++){
      int dd = t + j*256;
      #pragma unroll
      for (int h=0;h<NH;h++) sacc[j][h] *= scS[h];
      for (int k=0;k<25;k++){
        float nv = bf2f(nkS[k*772+dd]);
        float w0,w1,w2,w3,w4,w5,w6,w7;
        w0=sc[0*32+k]; w1=sc[1*32+k]; w2=sc[2*32+k]; w3=sc[3*32+k];
        w4=sc[4*32+k]; w5=sc[5*32+k]; w6=sc[6*32+k]; w7=sc[7*32+k];
        sacc[j][0]+=w0*nv; sacc[j][1]+=w1*nv; sacc[j][2]+=w2*nv; sacc[j][3]+=w3*nv;
        sacc[j][4]+=w4*nv; sacc[j][5]+=w5*nv; sacc[j][6]+=w6*nv; sacc[j][7]+=w7*nv;
      }
    }
  }
  float inv[NH];
  #pragma unroll
  for (int h=0;h<NH;h++) inv[h] = 1.f/dh[h];
  #pragma unroll
  for (int j=0;j<3;j++){
    int dd = t + j*256;
    #pragma unroll
    for (int h=0;h<NH;h++) sb[(long)b*NH*ND + h*ND + dd] = f2bf(sacc[j][h]*inv[h]);
  }
  if (t < 64){
    float num=0.f, den=0.f;
    if (t < NK){
      float d = dists[b*NK+t];
      float v = mvals[selS[t]];
      float e = __expf(-d*meanbuf[1]);
      num = e*v; den = e;
    }
    #pragma unroll
    for (int o=32;o;o>>=1){ num += __shfl_down(num,o); den += __shfl_down(den,o); }
    if (t==0) out_rag[b] = num/den;
  }
}

// ---------------- gate output ----------------
__global__ void gate2_kernel(const float* __restrict__ hg, const float* __restrict__ Wg2,
                             const float* __restrict__ bg2, float* __restrict__ outg){
  int b = blockIdx.x*4 + (threadIdx.x>>6);
  int l = threadIdx.x & 63;
  float s=0.f;
  for (int i=l;i<256;i+=64) s += hg[(long)b*256+i]*Wg2[i];
  #pragma unroll
  for (int o=32;o;o>>=1) s += __shfl_down(s,o);
  if (l==0) outg[b] = 1.f/(1.f+__expf(-(s+bg2[0])));
}

extern "C" void kernel_launch(void* const* d_in, const int* in_sizes, int n_in,
                              void* d_out, int out_size, void* d_ws, size_t ws_size,
                              hipStream_t stream){
  const float* query = (const float*)d_in[0];
  const float* mkeys = (const float*)d_in[1];
  const float* mvals = (const float*)d_in[2];
  const float* Wq  = (const float*)d_in[3];
  const float* bq  = (const float*)d_in[4];
  const float* Wk  = (const float*)d_in[5];
  const float* Wv  = (const float*)d_in[7];
  const float* bv  = (const float*)d_in[8];
  const float* Wo  = (const float*)d_in[9];
  const float* bo  = (const float*)d_in[10];
  const float* Wg1 = (const float*)d_in[11];
  const float* bg1 = (const float*)d_in[12];
  const float* Wg2 = (const float*)d_in[13];
  const float* bg2 = (const float*)d_in[14];
  float* out = (float*)d_out;           // f32: [enhanced B*768 | rag B | gate B]

  char* ws = (char*)d_ws;
  size_t off = 0;
  auto alloc = [&](size_t bytes)->char*{ char* p = ws + off; off += (bytes + 255) & ~(size_t)255; return p; };

  u16*   mkb   = (u16*)  alloc((size_t)NM*ND*2);
  u16*   qb    = (u16*)  alloc((size_t)NB*ND*2);
  u16*   comb  = (u16*)  alloc((size_t)NB*2*ND*2);
  float* q2    = (float*)alloc(NB*4);
  float* m2    = (float*)alloc(NM*4);
  u16*   wqb   = (u16*)  alloc((size_t)ND*ND*2);
  u16*   wkt   = (u16*)  alloc((size_t)ND*ND*2);
  u16*   wvb   = (u16*)  alloc((size_t)ND*ND*2);
  u16*   wob   = (u16*)  alloc((size_t)ND*ND*2);
  u16*   wg1b  = (u16*)  alloc((size_t)256*2*ND*2);
  float* d2s   = (float*)alloc((size_t)NB*SAMP*4);   // aliased below by cand arrays (d2s dead after find_thr)
  float* thr   = (float*)alloc(NB*4);
  int*   cnt   = (int*)  alloc(NB*4);
  int*   sel   = (int*)  alloc((size_t)NB*NK*4);
  float* dists = (float*)alloc((size_t)NB*NK*4);
  float* dsum  = (float*)alloc(NB*4);
  float* meanbuf=(float*)alloc(256);
  u16*   qpb   = (u16*)  alloc((size_t)NB*ND*2);
  u16*   ubuf  = (u16*)  alloc((size_t)NB*NH*ND*2);
  u16*   sbuf  = (u16*)  alloc((size_t)NB*NH*ND*2);
  u16*   ctx2b = (u16*)  alloc((size_t)NB*ND*2);
  float* hg    = (float*)alloc((size_t)NB*256*4);
  // alias: cand buffers live in d2s region (16.8MB; cand needs 8.4+8.4MB); stream-ordered safe
  float* cand_d2 = d2s;
  int*   cand_idx= (int*)(d2s + (size_t)NB*CAP);
  (void)ws_size; (void)in_sizes; (void)n_in; (void)out_size;

  // prep
  prep_query<<<NB/4, 256, 0, stream>>>(query, qb, q2, comb);
  prep_mk<<<NM/4, 256, 0, stream>>>(mkeys, mkb, m2);
  cvt_bf<<<(ND*ND+255)/256, 256, 0, stream>>>(Wq, wqb, ND*ND);
  cvt_bf<<<(ND*ND+255)/256, 256, 0, stream>>>(Wv, wvb, ND*ND);
  cvt_bf<<<(ND*ND+255)/256, 256, 0, stream>>>(Wo, wob, ND*ND);
  cvt_bf<<<(256*2*ND+255)/256, 256, 0, stream>>>(Wg1, wg1b, 256*2*ND);
  transpose_wk<<<(ND*ND+255)/256, 256, 0, stream>>>(Wk, wkt);

  // retrieval: sample -> threshold -> filtered candidates -> exact top-50
  // grids are 1-D XCD-swizzled: bid = y%8 + 8*(x + 8*(y/8)); ny=32 -> 256 blocks, ny=391 -> 3136
  gemm_rs<2><<<256, 256, 0, stream>>>(qb,ND, mkb,ND, SAMP,ND,32,
      d2s,SAMP, q2,m2,nullptr, nullptr,nullptr,nullptr);
  find_thr<<<NB, 256, 0, stream>>>(d2s, thr);
  hipMemsetAsync(cnt, 0, NB*sizeof(int), stream);
  gemm_rs<3><<<3136, 256, 0, stream>>>(qb,ND, mkb,ND, NM,ND,391,
      nullptr,0, q2,m2,thr, cand_d2,cand_idx,cnt);
  select50<<<NB, 256, 0, stream>>>(cand_d2, cand_idx, cnt, sel, dists, dsum);
  mean_kernel<<<1, 256, 0, stream>>>(dsum, meanbuf);

  // q-projection, then u[b,h,:] = Wk_h^T @ q_h  (collapses K-projection)
  gemm_dma<1><<<dim3(NB/128, ND/128, 1), 256, 0, stream>>>(qb,ND,0, wqb,ND,0, ND,ND,
      nullptr,qpb,ND,0, bq,0, nullptr,nullptr,0);
  gemm_dma<1><<<dim3(NB/128, ND/128, NH), 256, 0, stream>>>(qpb,ND,96, wkt,96,(long)ND*96, ND,96,
      nullptr,ubuf,NH*ND,ND, nullptr,0, nullptr,nullptr,0);

  // attention scores/softmax/weighted-neighbor-sum + rag prediction
  attn_kernel<<<NB, 256, 0, stream>>>(sel, mkb, ubuf, dists, mvals, meanbuf, sbuf, out + (size_t)NB*ND);

  // ctx2[b,h*96+hd] = Wv_h @ s_h + bv   (collapses V-projection; exact since sum(attn)=1)
  gemm_dma<1><<<dim3(NB/128, 1, NH), 256, 0, stream>>>(sbuf,NH*ND,ND, wvb,ND,(long)96*ND, 96,ND,
      nullptr,ctx2b,ND,96, bv,96, nullptr,nullptr,0);

  // context = ctx2 @ Wo^T + bo; enhanced (f32) = query + context -> out; context -> combined[:,768:]
  gemm_dma<4><<<dim3(NB/128, ND/128, 1), 256, 0, stream>>>(ctx2b,ND,0, wob,ND,0, ND,ND,
      out,nullptr,ND,0, bo,0, query, comb+ND, 2*ND);

  // gate MLP
  gemm_dma<0><<<dim3(NB/128, 2, 1), 256, 0, stream>>>(comb,2*ND,0, wg1b,2*ND,0, 256,2*ND,
      hg,nullptr,256,0, bg1,0, nullptr,nullptr,0);
  gate2_kernel<<<NB/4, 256, 0, stream>>>(hg, Wg2, bg2, out + (size_t)NB*ND + NB);
}

// Round 6
// 869.362 us; speedup vs baseline: 1.3433x; 1.0139x over previous
//
#include <hip/hip_runtime.h>

typedef unsigned int u32;
typedef unsigned short u16;
typedef unsigned long long u64;
typedef __bf16 bf16x8 __attribute__((ext_vector_type(8)));
typedef float f32x4 __attribute__((ext_vector_type(4)));

#define DEVI __device__ __forceinline__

DEVI u16 f2bf(float x){ u32 u = __builtin_bit_cast(u32, x); return (u16)((u + 0x7fffu + ((u>>16)&1u)) >> 16); }
DEVI float bf2f(u16 h){ return __builtin_bit_cast(float, ((u32)h)<<16); }

// constants
#define NB 1024
#define ND 768
#define NM 50000
#define NK 50
#define NH 8
#define SAMP 4096
#define RSEL 25
#define CAP 2048

// ---------------- prep: wave-per-row f32 -> bf16 + sumsq ----------------
__global__ __launch_bounds__(256) void prep_mk(const float* __restrict__ src, u16* __restrict__ dst,
                                               float* __restrict__ nrm2){
  int r = blockIdx.x*4 + (threadIdx.x>>6);
  int l = threadIdx.x & 63;
  const float4* s4 = (const float4*)(src + (long)r*ND);
  u32* d = (u32*)(dst + (long)r*ND);
  float ss = 0.f;
  #pragma unroll
  for (int j=0;j<3;j++){
    float4 v = s4[l + j*64];
    ss += v.x*v.x + v.y*v.y + v.z*v.z + v.w*v.w;
    d[(l+j*64)*2]   = ((u32)f2bf(v.y)<<16) | f2bf(v.x);
    d[(l+j*64)*2+1] = ((u32)f2bf(v.w)<<16) | f2bf(v.z);
  }
  #pragma unroll
  for (int o=32;o;o>>=1) ss += __shfl_down(ss,o);
  if (l==0) nrm2[r]=ss;
}

__global__ __launch_bounds__(256) void prep_query(const float* __restrict__ src, u16* __restrict__ qb,
                                                  float* __restrict__ q2, u16* __restrict__ comb){
  int r = blockIdx.x*4 + (threadIdx.x>>6);
  int l = threadIdx.x & 63;
  const float4* s4 = (const float4*)(src + (long)r*ND);
  u32* dq = (u32*)(qb + (long)r*ND);
  u32* dc = (u32*)(comb + (long)r*2*ND);
  float ss = 0.f;
  #pragma unroll
  for (int j=0;j<3;j++){
    float4 v = s4[l + j*64];
    ss += v.x*v.x + v.y*v.y + v.z*v.z + v.w*v.w;
    u32 p0 = ((u32)f2bf(v.y)<<16) | f2bf(v.x);
    u32 p1 = ((u32)f2bf(v.w)<<16) | f2bf(v.z);
    dq[(l+j*64)*2]=p0; dq[(l+j*64)*2+1]=p1;
    dc[(l+j*64)*2]=p0; dc[(l+j*64)*2+1]=p1;
  }
  #pragma unroll
  for (int o=32;o;o>>=1) ss += __shfl_down(ss,o);
  if (l==0) q2[r]=ss;
}

__global__ void cvt_bf(const float* __restrict__ s, u16* __restrict__ d, int n){
  int i = blockIdx.x*256 + threadIdx.x;
  if (i<n) d[i] = f2bf(s[i]);
}

// wkt[h][d][hd] = Wk[h*96+hd][d]
__global__ void transpose_wk(const float* __restrict__ Wk, u16* __restrict__ wkt){
  int i = blockIdx.x*256 + threadIdx.x;
  if (i >= NH*ND*96) return;
  int h = i / (ND*96); int rem = i % (ND*96); int d = rem / 96; int hd = rem % 96;
  wkt[i] = f2bf(Wk[(long)(h*96+hd)*ND + d]);
}

// ============ unified bf16 A@B^T MFMA GEMM, 128x128x32 tile, 4 waves ============
// Single-barrier double-buffered pipeline: per K-step
//   ds_write(buf) -> s_waitcnt lgkmcnt(0) -> s_barrier -> issue global loads tile+2
//   -> ds_read(buf) + 16 MFMA.
// Raw s_barrier (NOT __syncthreads) so the 2-deep register prefetch stays in flight
// across barriers (no vmcnt drain). Buffer reuse is safe: >=1 barrier between any
// compute(buf) and the next store(buf), and each wave's ds_reads are lgkm-drained
// before it enters that barrier.
// MODE 0: C f32 = relu(acc + bias)         (gate hidden)
// MODE 1: C bf16 = acc + bias              (qp / u / ctx2)
// MODE 2: C f32 = d2 = q2[r]+m2[c]-2acc    (sample distances)
// MODE 3: candidate filter: d2 <= thr[r] -> atomic append
// MODE 4: ctx = acc + bias; out2 = bf16(ctx); Cf f32 = qsrc + ctx  (Wo epilogue)
// SWZ: 1-D XCD-aware grid decode (all 8 M-tiles of an N-panel on one XCD, adjacent).
template<int MODE, int SWZ>
__global__ __launch_bounds__(256)
void gemm_uni(const u16* __restrict__ A, int lda, long az,
              const u16* __restrict__ Bm, int ldb, long bz,
              int Ndim, int Kdim, int ny,
              float* __restrict__ Cf, u16* __restrict__ Cb, int ldc, long cz,
              const float* __restrict__ bias, long biasz,
              const float* __restrict__ q2, const float* __restrict__ m2, const float* __restrict__ thr,
              float* __restrict__ cand_d2, int* __restrict__ cand_idx, int* __restrict__ cnt,
              const float* __restrict__ qsrc, u16* __restrict__ out2, int ldo2)
{
  int m0, n0, z = 0;
  if (SWZ){
    const int cxcd = blockIdx.x & 7, j = blockIdx.x >> 3;
    const int xt = j & 7, yhi = j >> 3;
    const int y = yhi*8 + cxcd;
    if (y >= ny) return;
    m0 = xt*128; n0 = y*128;
  } else {
    m0 = blockIdx.x*128; n0 = blockIdx.y*128; z = blockIdx.z;
    A += (long)z*az; Bm += (long)z*bz;
  }

  const int t = threadIdx.x;
  const int lane = t & 63, wid = t >> 6;
  __shared__ u16 As[2][128*32], Bs[2][128*32];
  f32x4 acc[4][4];
  #pragma unroll
  for (int m=0;m<4;m++)
    #pragma unroll
    for (int n=0;n<4;n++) acc[m][n] = f32x4{0.f,0.f,0.f,0.f};

  const int wr = (wid>>1)*64, wc = (wid&1)*64;
  const int sr = t>>2, sc4 = t&3;
  const int r0 = sr, r1 = sr+64;
  const int sl0 = (sc4 ^ ((r0>>1)&3))*8, sl1 = (sc4 ^ ((r1>>1)&3))*8;  // XOR swizzle slots
  int jb0 = n0+r0; if (jb0>=Ndim) jb0=Ndim-1;
  int jb1 = n0+r1; if (jb1>=Ndim) jb1=Ndim-1;
  const u16* pa0 = &A[(long)(m0+r0)*lda + sc4*8];
  const u16* pa1 = &A[(long)(m0+r1)*lda + sc4*8];
  const u16* pb0 = &Bm[(long)jb0*ldb + sc4*8];
  const u16* pb1 = &Bm[(long)jb1*ldb + sc4*8];

  uint4 pA0,pA1,pB0,pB1, qA0,qA1,qB0,qB1;
  #define LOADG(S, K0) { S##A0 = *(const uint4*)(pa0+(K0)); S##A1 = *(const uint4*)(pa1+(K0)); \
                         S##B0 = *(const uint4*)(pb0+(K0)); S##B1 = *(const uint4*)(pb1+(K0)); }
  #define STORELDS(BUF, S) { *(uint4*)&As[BUF][r0*32+sl0] = S##A0; *(uint4*)&As[BUF][r1*32+sl1] = S##A1; \
                             *(uint4*)&Bs[BUF][r0*32+sl0] = S##B0; *(uint4*)&Bs[BUF][r1*32+sl1] = S##B1; }

  auto compute = [&](const u16* __restrict__ Ab, const u16* __restrict__ Bb){
    bf16x8 af[4], bfr[4];
    #pragma unroll
    for (int m=0;m<4;m++){
      int row = wr + m*16 + (lane&15);
      int slot = ((lane>>4) ^ ((row>>1)&3));
      af[m] = __builtin_bit_cast(bf16x8, *(const uint4*)&Ab[row*32 + slot*8]);
    }
    #pragma unroll
    for (int n=0;n<4;n++){
      int row = wc + n*16 + (lane&15);
      int slot = ((lane>>4) ^ ((row>>1)&3));
      bfr[n] = __builtin_bit_cast(bf16x8, *(const uint4*)&Bb[row*32 + slot*8]);
    }
    #pragma unroll
    for (int m=0;m<4;m++)
      #pragma unroll
      for (int n=0;n<4;n++)
        acc[m][n] = __builtin_amdgcn_mfma_f32_16x16x32_bf16(af[m], bfr[n], acc[m][n], 0,0,0);
  };

  const int nt = Kdim >> 5;
  LOADG(p, 0);
  if (nt > 1) LOADG(q, 32);
  #pragma unroll 1
  for (int ti=0; ti<nt; ti+=2){
    STORELDS(0, p);
    asm volatile("s_waitcnt lgkmcnt(0)" ::: "memory");
    __builtin_amdgcn_s_barrier();
    if (ti+2 < nt) LOADG(p, (ti+2)*32);
    compute(As[0], Bs[0]);
    if (ti+1 < nt){
      STORELDS(1, q);
      asm volatile("s_waitcnt lgkmcnt(0)" ::: "memory");
      __builtin_amdgcn_s_barrier();
      if (ti+3 < nt) LOADG(q, (ti+3)*32);
      compute(As[1], Bs[1]);
    }
  }
  #undef LOADG
  #undef STORELDS

  const float* bz_p = ((MODE==0)||(MODE==1)||(MODE==4)) && bias ? bias + (long)z*biasz : nullptr;
  #pragma unroll
  for (int m=0;m<4;m++){
    #pragma unroll
    for (int n=0;n<4;n++){
      #pragma unroll
      for (int q=0;q<4;q++){
        int r = m0 + wr + m*16 + ((lane>>4)<<2) + q;
        int c = n0 + wc + n*16 + (lane&15);
        float v = acc[m][n][q];
        if (MODE==0){
          if (c<Ndim){ if(bz_p) v += bz_p[c]; Cf[(long)r*ldc + (long)z*cz + c] = fmaxf(v,0.f); }
        } else if (MODE==1){
          if (c<Ndim){ if(bz_p) v += bz_p[c]; Cb[(long)r*ldc + (long)z*cz + c] = f2bf(v); }
        } else if (MODE==2){
          if (c<Ndim){ float d2 = fmaxf(q2[r]+m2[c]-2.f*v, 0.f); Cf[(long)r*ldc + c] = d2; }
        } else if (MODE==3){
          if (c<Ndim){
            float d2 = fmaxf(q2[r]+m2[c]-2.f*v, 0.f);
            if (d2 <= thr[r]){
              int p = atomicAdd(&cnt[r],1);
              if (p < CAP){ cand_d2[(long)r*CAP+p]=d2; cand_idx[(long)r*CAP+p]=c; }
            }
          }
        } else {
          if (c<Ndim){
            float ctx = v + (bz_p?bz_p[c]:0.f);
            out2[(long)r*ldo2 + c] = f2bf(ctx);
            Cf[(long)r*ldc + c] = qsrc[(long)r*ND+c] + ctx;   // enhanced, f32
          }
        }
      }
    }
  }
}

// ---------------- per-query threshold: per-wave bisection for 25th-smallest, min over waves ----------------
__global__ __launch_bounds__(256) void find_thr(const float* __restrict__ d2s, float* __restrict__ thr){
  int b = blockIdx.x, w = threadIdx.x>>6, l = threadIdx.x&63;
  const float4* base = (const float4*)(d2s + (long)b*SAMP + w*1024);
  float v[16];
  #pragma unroll
  for (int j=0;j<4;j++){
    float4 q = base[l*4+j];
    v[j*4]=q.x; v[j*4+1]=q.y; v[j*4+2]=q.z; v[j*4+3]=q.w;
  }
  u32 lo=0, hi=0x7f7fffffu;
  for (int it=0; it<28; ++it){
    u32 mid = (lo+hi)>>1;
    float fm = __builtin_bit_cast(float, mid);
    int c=0;
    #pragma unroll
    for (int j=0;j<16;j++) c += (v[j] <= fm) ? 1 : 0;
    #pragma unroll
    for (int o=32;o;o>>=1) c += __shfl_down(c,o);
    c = __shfl(c,0);
    if (c >= RSEL) hi = mid; else lo = mid+1;
  }
  __shared__ float wt[4];
  if (l==0) wt[w] = __builtin_bit_cast(float, hi);
  __syncthreads();
  if (threadIdx.x==0) thr[b] = fminf(fminf(wt[0],wt[1]), fminf(wt[2],wt[3]));
}

// ---------------- exact top-50: parallel rank-count over candidates ----------------
__global__ __launch_bounds__(256) void select50(const float* __restrict__ cand_d2, const int* __restrict__ cand_idx,
                                                const int* __restrict__ cnt, int* __restrict__ sel,
                                                float* __restrict__ dists, float* __restrict__ dsum){
  int b = blockIdx.x, t = threadIdx.x;
  __shared__ u64 arr[CAP];
  __shared__ float dS[NK];
  int n = cnt[b]; if (n > CAP) n = CAP;
  for (int i=t;i<n;i+=256){
    float d2 = fmaxf(cand_d2[(long)b*CAP+i],0.f);
    arr[i] = ((u64)__builtin_bit_cast(u32, d2)<<32) | (u32)cand_idx[(long)b*CAP+i];
  }
  if (t < NK){ dS[t]=0.f; sel[b*NK+t]=0; dists[b*NK+t]=0.f; }  // safety init (n<50 ~impossible)
  __syncthreads();
  for (int i=t;i<n;i+=256){
    u64 me = arr[i];
    int rank = 0;
    for (int j=0;j<n;j++) rank += (arr[j] < me) ? 1 : 0;   // unique keys -> unique ranks
    if (rank < NK){
      float d = sqrtf(__builtin_bit_cast(float, (u32)(me>>32)));
      sel[b*NK+rank] = (int)(u32)(me & 0xffffffffu);
      dists[b*NK+rank] = d;
      dS[rank] = d;
    }
  }
  __syncthreads();
  if (t==0){ float s=0.f; for (int r=0;r<NK;r++) s+=dS[r]; dsum[b]=s; }
}

__global__ void mean_kernel(const float* __restrict__ dsum, float* __restrict__ meanbuf){
  int t = threadIdx.x;
  float s=0.f; for (int i=t;i<NB;i+=256) s += dsum[i];
  __shared__ float red[256];
  red[t]=s; __syncthreads();
  #pragma unroll
  for (int st=128;st>0;st>>=1){ if(t<st) red[t]+=red[t+st]; __syncthreads(); }
  if (t==0){ float mean = red[0]/(float)(NB*NK); meanbuf[0]=mean; meanbuf[1]=1.f/mean; }
}

// ---------------- per-query attention: online softmax, bf16 gathers, + rag ----------------
__global__ __launch_bounds__(256) void attn_kernel(
    const int* __restrict__ sel, const u16* __restrict__ mkb,
    const u16* __restrict__ ub, const float* __restrict__ dists,
    const float* __restrict__ mvals, const float* __restrict__ meanbuf,
    u16* __restrict__ sb, float* __restrict__ out_rag)
{
  const int b = blockIdx.x, t = threadIdx.x;
  __shared__ u16 nkS[25*772];
  __shared__ u16 uS[8*772];
  __shared__ float sc[NH*32];
  __shared__ float mh[NH], dh[NH], scS[NH];
  __shared__ int selS[NK];
  if (t < NK) selS[t] = sel[b*NK+t];
  if (t >= 64 && t < 64+NH){ mh[t-64] = -1e30f; dh[t-64] = 0.f; }
  {
    const u32* src = (const u32*)&ub[(long)b*NH*ND];
    for (int i=t;i<NH*(ND/2);i+=256){
      int h = i/(ND/2), d = i%(ND/2);
      ((u32*)&uS[h*772])[d] = src[h*(ND/2)+d];
    }
  }
  float sacc[3][NH];
  #pragma unroll
  for (int j=0;j<3;j++)
    #pragma unroll
    for (int h=0;h<NH;h++) sacc[j][h]=0.f;
  const float rs = 0.10206207261596575f;  // 1/sqrt(96)

  for (int half=0; half<2; ++half){
    __syncthreads();
    for (int k=0;k<25;k++){
      const u32* src = (const u32*)&mkb[(long)selS[half*25+k]*ND];
      u32* dst = (u32*)&nkS[k*772];
      for (int i=t;i<ND/2;i+=256) dst[i] = src[i];
    }
    __syncthreads();
    if (t < 200){
      const u32* nr = (const u32*)&nkS[(t%25)*772];
      const u32* ur = (const u32*)&uS[(t/25)*772];
      float acc = 0.f;
      #pragma unroll 8
      for (int d=0; d<ND/2; d++){
        u32 a = nr[d], uu = ur[d];
        acc += bf2f((u16)a)*bf2f((u16)uu) + bf2f((u16)(a>>16))*bf2f((u16)(uu>>16));
      }
      sc[(t/25)*32 + (t%25)] = acc*rs;
    }
    __syncthreads();
    if (t < NH){
      float mn = mh[t];
      #pragma unroll
      for (int k=0;k<25;k++) mn = fmaxf(mn, sc[t*32+k]);
      float scale = __expf(mh[t]-mn);
      float d = dh[t]*scale;
      #pragma unroll
      for (int k=0;k<25;k++){ float e = __expf(sc[t*32+k]-mn); sc[t*32+k]=e; d+=e; }
      mh[t]=mn; dh[t]=d; scS[t]=scale;
    }
    __syncthreads();
    #pragma unroll
    for (int j=0;j<3;j++){
      int dd = t + j*256;
      #pragma unroll
      for (int h=0;h<NH;h++) sacc[j][h] *= scS[h];
      for (int k=0;k<25;k++){
        float nv = bf2f(nkS[k*772+dd]);
        float w0,w1,w2,w3,w4,w5,w6,w7;
        w0=sc[0*32+k]; w1=sc[1*32+k]; w2=sc[2*32+k]; w3=sc[3*32+k];
        w4=sc[4*32+k]; w5=sc[5*32+k]; w6=sc[6*32+k]; w7=sc[7*32+k];
        sacc[j][0]+=w0*nv; sacc[j][1]+=w1*nv; sacc[j][2]+=w2*nv; sacc[j][3]+=w3*nv;
        sacc[j][4]+=w4*nv; sacc[j][5]+=w5*nv; sacc[j][6]+=w6*nv; sacc[j][7]+=w7*nv;
      }
    }
  }
  float inv[NH];
  #pragma unroll
  for (int h=0;h<NH;h++) inv[h] = 1.f/dh[h];
  #pragma unroll
  for (int j=0;j<3;j++){
    int dd = t + j*256;
    #pragma unroll
    for (int h=0;h<NH;h++) sb[(long)b*NH*ND + h*ND + dd] = f2bf(sacc[j][h]*inv[h]);
  }
  if (t < 64){
    float num=0.f, den=0.f;
    if (t < NK){
      float d = dists[b*NK+t];
      float v = mvals[selS[t]];
      float e = __expf(-d*meanbuf[1]);
      num = e*v; den = e;
    }
    #pragma unroll
    for (int o=32;o;o>>=1){ num += __shfl_down(num,o); den += __shfl_down(den,o); }
    if (t==0) out_rag[b] = num/den;
  }
}

// ---------------- gate output ----------------
__global__ void gate2_kernel(const float* __restrict__ hg, const float* __restrict__ Wg2,
                             const float* __restrict__ bg2, float* __restrict__ outg){
  int b = blockIdx.x*4 + (threadIdx.x>>6);
  int l = threadIdx.x & 63;
  float s=0.f;
  for (int i=l;i<256;i+=64) s += hg[(long)b*256+i]*Wg2[i];
  #pragma unroll
  for (int o=32;o;o>>=1) s += __shfl_down(s,o);
  if (l==0) outg[b] = 1.f/(1.f+__expf(-(s+bg2[0])));
}

extern "C" void kernel_launch(void* const* d_in, const int* in_sizes, int n_in,
                              void* d_out, int out_size, void* d_ws, size_t ws_size,
                              hipStream_t stream){
  const float* query = (const float*)d_in[0];
  const float* mkeys = (const float*)d_in[1];
  const float* mvals = (const float*)d_in[2];
  const float* Wq  = (const float*)d_in[3];
  const float* bq  = (const float*)d_in[4];
  const float* Wk  = (const float*)d_in[5];
  const float* Wv  = (const float*)d_in[7];
  const float* bv  = (const float*)d_in[8];
  const float* Wo  = (const float*)d_in[9];
  const float* bo  = (const float*)d_in[10];
  const float* Wg1 = (const float*)d_in[11];
  const float* bg1 = (const float*)d_in[12];
  const float* Wg2 = (const float*)d_in[13];
  const float* bg2 = (const float*)d_in[14];
  float* out = (float*)d_out;           // f32: [enhanced B*768 | rag B | gate B]

  char* ws = (char*)d_ws;
  size_t off = 0;
  auto alloc = [&](size_t bytes)->char*{ char* p = ws + off; off += (bytes + 255) & ~(size_t)255; return p; };

  u16*   mkb   = (u16*)  alloc((size_t)NM*ND*2);
  u16*   qb    = (u16*)  alloc((size_t)NB*ND*2);
  u16*   comb  = (u16*)  alloc((size_t)NB*2*ND*2);
  float* q2    = (float*)alloc(NB*4);
  float* m2    = (float*)alloc(NM*4);
  u16*   wqb   = (u16*)  alloc((size_t)ND*ND*2);
  u16*   wkt   = (u16*)  alloc((size_t)ND*ND*2);
  u16*   wvb   = (u16*)  alloc((size_t)ND*ND*2);
  u16*   wob   = (u16*)  alloc((size_t)ND*ND*2);
  u16*   wg1b  = (u16*)  alloc((size_t)256*2*ND*2);
  float* d2s   = (float*)alloc((size_t)NB*SAMP*4);   // aliased below by cand arrays (d2s dead after find_thr)
  float* thr   = (float*)alloc(NB*4);
  int*   cnt   = (int*)  alloc(NB*4);
  int*   sel   = (int*)  alloc((size_t)NB*NK*4);
  float* dists = (float*)alloc((size_t)NB*NK*4);
  float* dsum  = (float*)alloc(NB*4);
  float* meanbuf=(float*)alloc(256);
  u16*   qpb   = (u16*)  alloc((size_t)NB*ND*2);
  u16*   ubuf  = (u16*)  alloc((size_t)NB*NH*ND*2);
  u16*   sbuf  = (u16*)  alloc((size_t)NB*NH*ND*2);
  u16*   ctx2b = (u16*)  alloc((size_t)NB*ND*2);
  float* hg    = (float*)alloc((size_t)NB*256*4);
  // alias: cand buffers live in d2s region (16.8MB; cand needs 8.4+8.4MB); stream-ordered safe
  float* cand_d2 = d2s;
  int*   cand_idx= (int*)(d2s + (size_t)NB*CAP);
  (void)ws_size; (void)in_sizes; (void)n_in; (void)out_size;

  // prep
  prep_query<<<NB/4, 256, 0, stream>>>(query, qb, q2, comb);
  prep_mk<<<NM/4, 256, 0, stream>>>(mkeys, mkb, m2);
  cvt_bf<<<(ND*ND+255)/256, 256, 0, stream>>>(Wq, wqb, ND*ND);
  cvt_bf<<<(ND*ND+255)/256, 256, 0, stream>>>(Wv, wvb, ND*ND);
  cvt_bf<<<(ND*ND+255)/256, 256, 0, stream>>>(Wo, wob, ND*ND);
  cvt_bf<<<(256*2*ND+255)/256, 256, 0, stream>>>(Wg1, wg1b, 256*2*ND);
  transpose_wk<<<(ND*ND+255)/256, 256, 0, stream>>>(Wk, wkt);

  // retrieval: sample -> threshold -> filtered candidates -> exact top-50
  // grids are 1-D XCD-swizzled: bid = y%8 + 8*(x + 8*(y/8)); ny=32 -> 256 blocks, ny=391 -> 3136
  gemm_uni<2,1><<<256, 256, 0, stream>>>(qb,ND,0, mkb,ND,0, SAMP,ND,32,
      d2s,nullptr,SAMP,0, nullptr,0, q2,m2,nullptr, nullptr,nullptr,nullptr, nullptr,nullptr,0);
  find_thr<<<NB, 256, 0, stream>>>(d2s, thr);
  hipMemsetAsync(cnt, 0, NB*sizeof(int), stream);
  gemm_uni<3,1><<<3136, 256, 0, stream>>>(qb,ND,0, mkb,ND,0, NM,ND,391,
      nullptr,nullptr,0,0, nullptr,0, q2,m2,thr, cand_d2,cand_idx,cnt, nullptr,nullptr,0);
  select50<<<NB, 256, 0, stream>>>(cand_d2, cand_idx, cnt, sel, dists, dsum);
  mean_kernel<<<1, 256, 0, stream>>>(dsum, meanbuf);

  // q-projection, then u[b,h,:] = Wk_h^T @ q_h  (collapses K-projection)
  gemm_uni<1,0><<<dim3(NB/128, ND/128, 1), 256, 0, stream>>>(qb,ND,0, wqb,ND,0, ND,ND,0,
      nullptr,qpb,ND,0, bq,0, nullptr,nullptr,nullptr, nullptr,nullptr,nullptr, nullptr,nullptr,0);
  gemm_uni<1,0><<<dim3(NB/128, ND/128, NH), 256, 0, stream>>>(qpb,ND,96, wkt,96,(long)ND*96, ND,96,0,
      nullptr,ubuf,NH*ND,ND, nullptr,0, nullptr,nullptr,nullptr, nullptr,nullptr,nullptr, nullptr,nullptr,0);

  // attention scores/softmax/weighted-neighbor-sum + rag prediction
  attn_kernel<<<NB, 256, 0, stream>>>(sel, mkb, ubuf, dists, mvals, meanbuf, sbuf, out + (size_t)NB*ND);

  // ctx2[b,h*96+hd] = Wv_h @ s_h + bv   (collapses V-projection; exact since sum(attn)=1)
  gemm_uni<1,0><<<dim3(NB/128, 1, NH), 256, 0, stream>>>(sbuf,NH*ND,ND, wvb,ND,(long)96*ND, 96,ND,0,
      nullptr,ctx2b,ND,96, bv,96, nullptr,nullptr,nullptr, nullptr,nullptr,nullptr, nullptr,nullptr,0);

  // context = ctx2 @ Wo^T + bo; enhanced (f32) = query + context -> out; context -> combined[:,768:]
  gemm_uni<4,0><<<dim3(NB/128, ND/128, 1), 256, 0, stream>>>(ctx2b,ND,0, wob,ND,0, ND,ND,0,
      out,nullptr,ND,0, bo,0, nullptr,nullptr,nullptr, nullptr,nullptr,nullptr, query, comb+ND, 2*ND);

  // gate MLP
  gemm_uni<0,0><<<dim3(NB/128, 2, 1), 256, 0, stream>>>(comb,2*ND,0, wg1b,2*ND,0, 256,2*ND,0,
      hg,nullptr,256,0, bg1,0, nullptr,nullptr,nullptr, nullptr,nullptr,nullptr, nullptr,nullptr,0);
  gate2_kernel<<<NB/4, 256, 0, stream>>>(hg, Wg2, bg2, out + (size_t)NB*ND + NB);
}

// Round 7
// 831.913 us; speedup vs baseline: 1.4038x; 1.0450x over previous
//
#include <hip/hip_runtime.h>

typedef unsigned int u32;
typedef unsigned short u16;
typedef unsigned long long u64;
typedef __bf16 bf16x8 __attribute__((ext_vector_type(8)));
typedef float f32x4 __attribute__((ext_vector_type(4)));

#define DEVI __device__ __forceinline__

DEVI u16 f2bf(float x){ u32 u = __builtin_bit_cast(u32, x); return (u16)((u + 0x7fffu + ((u>>16)&1u)) >> 16); }
DEVI float bf2f(u16 h){ return __builtin_bit_cast(float, ((u32)h)<<16); }

// constants
#define NB 1024
#define ND 768
#define NM 50000
#define NK 50
#define NH 8
#define SAMP 4096
#define RSEL 25
#define CAP 2048

// ---------------- prep: wave-per-row f32 -> bf16 + sumsq ----------------
__global__ __launch_bounds__(256) void prep_mk(const float* __restrict__ src, u16* __restrict__ dst,
                                               float* __restrict__ nrm2){
  int r = blockIdx.x*4 + (threadIdx.x>>6);
  int l = threadIdx.x & 63;
  const float4* s4 = (const float4*)(src + (long)r*ND);
  u32* d = (u32*)(dst + (long)r*ND);
  float ss = 0.f;
  #pragma unroll
  for (int j=0;j<3;j++){
    float4 v = s4[l + j*64];
    ss += v.x*v.x + v.y*v.y + v.z*v.z + v.w*v.w;
    d[(l+j*64)*2]   = ((u32)f2bf(v.y)<<16) | f2bf(v.x);
    d[(l+j*64)*2+1] = ((u32)f2bf(v.w)<<16) | f2bf(v.z);
  }
  #pragma unroll
  for (int o=32;o;o>>=1) ss += __shfl_down(ss,o);
  if (l==0) nrm2[r]=ss;
}

__global__ __launch_bounds__(256) void prep_query(const float* __restrict__ src, u16* __restrict__ qb,
                                                  float* __restrict__ q2, u16* __restrict__ comb){
  int r = blockIdx.x*4 + (threadIdx.x>>6);
  int l = threadIdx.x & 63;
  const float4* s4 = (const float4*)(src + (long)r*ND);
  u32* dq = (u32*)(qb + (long)r*ND);
  u32* dc = (u32*)(comb + (long)r*2*ND);
  float ss = 0.f;
  #pragma unroll
  for (int j=0;j<3;j++){
    float4 v = s4[l + j*64];
    ss += v.x*v.x + v.y*v.y + v.z*v.z + v.w*v.w;
    u32 p0 = ((u32)f2bf(v.y)<<16) | f2bf(v.x);
    u32 p1 = ((u32)f2bf(v.w)<<16) | f2bf(v.z);
    dq[(l+j*64)*2]=p0; dq[(l+j*64)*2+1]=p1;
    dc[(l+j*64)*2]=p0; dc[(l+j*64)*2+1]=p1;
  }
  #pragma unroll
  for (int o=32;o;o>>=1) ss += __shfl_down(ss,o);
  if (l==0) q2[r]=ss;
}

__global__ void cvt_bf(const float* __restrict__ s, u16* __restrict__ d, int n){
  int i = blockIdx.x*256 + threadIdx.x;
  if (i<n) d[i] = f2bf(s[i]);
}

// wkt[h][d][hd] = Wk[h*96+hd][d]
__global__ void transpose_wk(const float* __restrict__ Wk, u16* __restrict__ wkt){
  int i = blockIdx.x*256 + threadIdx.x;
  if (i >= NH*ND*96) return;
  int h = i / (ND*96); int rem = i % (ND*96); int d = rem / 96; int hd = rem % 96;
  wkt[i] = f2bf(Wk[(long)(h*96+hd)*ND + d]);
}

// ============ high-occupancy 64x128x32 GEMM, 2 waves/block, for the retrieval GEMMs ============
// Small blocks (12KB LDS, ~80 VGPR) -> ~8-12 resident blocks/CU -> 16-24 INDEPENDENT waves
// hide L3 load latency and epilogue atomic round-trips (Guideline 1). Simple 2-sync loop.
// 1-D XCD-swizzled grid: all 16 M-tiles of an N-panel on one XCD, temporally adjacent.
// MODE 2: C f32 = d2 = q2[r]+m2[c]-2acc   (sample distances)
// MODE 3: candidate filter: d2 <= thr[r] -> atomic append
template<int MODE>
__global__ __launch_bounds__(128)
void gemm64(const u16* __restrict__ A, int lda,
            const u16* __restrict__ Bm, int ldb,
            int Ndim, int Kdim, int ny,
            float* __restrict__ Cf, int ldc,
            const float* __restrict__ q2, const float* __restrict__ m2, const float* __restrict__ thr,
            float* __restrict__ cand_d2, int* __restrict__ cand_idx, int* __restrict__ cnt)
{
  const int cxcd = blockIdx.x & 7; const int j = blockIdx.x >> 3;
  const int xt = j & 15, yhi = j >> 4;
  const int y = yhi*8 + cxcd;
  if (y >= ny) return;
  const int m0 = xt*64, n0 = y*128;

  const int t = threadIdx.x;
  const int lane = t & 63, w = t >> 6;
  __shared__ u16 As[64*32], Bs[128*32];
  f32x4 acc[2][8];
  #pragma unroll
  for (int m=0;m<2;m++)
    #pragma unroll
    for (int n=0;n<8;n++) acc[m][n] = f32x4{0.f,0.f,0.f,0.f};

  // staging map: 128 threads; A 64 rows x 4 chunks (2/thread), B 128 rows x 4 chunks (4/thread)
  const int ra = t>>1, c0 = (t&1)*2, c1 = c0+1;
  const int rb1 = ra+64;
  const int sw = (ra>>1)&3;                 // same for ra and ra+64
  const int s0 = (c0^sw)*8, s1 = (c1^sw)*8; // XOR-swizzled LDS chunk slots
  int jb0 = n0+ra;  if (jb0>=Ndim) jb0=Ndim-1;
  int jb1 = n0+rb1; if (jb1>=Ndim) jb1=Ndim-1;
  const u16* pa  = &A[(long)(m0+ra)*lda + c0*8];
  const u16* pb0 = &Bm[(long)jb0*ldb + c0*8];
  const u16* pb1 = &Bm[(long)jb1*ldb + c0*8];

  for (int k0=0; k0<Kdim; k0+=32){
    __syncthreads();
    uint4 a0 = *(const uint4*)(pa + k0);
    uint4 a1 = *(const uint4*)(pa + k0 + 8);
    uint4 b00 = *(const uint4*)(pb0 + k0);
    uint4 b01 = *(const uint4*)(pb0 + k0 + 8);
    uint4 b10 = *(const uint4*)(pb1 + k0);
    uint4 b11 = *(const uint4*)(pb1 + k0 + 8);
    *(uint4*)&As[ra*32 + s0] = a0;
    *(uint4*)&As[ra*32 + s1] = a1;
    *(uint4*)&Bs[ra*32 + s0] = b00;
    *(uint4*)&Bs[ra*32 + s1] = b01;
    *(uint4*)&Bs[rb1*32 + s0] = b10;
    *(uint4*)&Bs[rb1*32 + s1] = b11;
    __syncthreads();
    bf16x8 af[2], bfr[8];
    #pragma unroll
    for (int m=0;m<2;m++){
      int row = w*32 + m*16 + (lane&15);
      int slot = ((lane>>4) ^ ((row>>1)&3));
      af[m] = __builtin_bit_cast(bf16x8, *(const uint4*)&As[row*32 + slot*8]);
    }
    #pragma unroll
    for (int n=0;n<8;n++){
      int row = n*16 + (lane&15);
      int slot = ((lane>>4) ^ ((row>>1)&3));
      bfr[n] = __builtin_bit_cast(bf16x8, *(const uint4*)&Bs[row*32 + slot*8]);
    }
    #pragma unroll
    for (int m=0;m<2;m++)
      #pragma unroll
      for (int n=0;n<8;n++)
        acc[m][n] = __builtin_amdgcn_mfma_f32_16x16x32_bf16(af[m], bfr[n], acc[m][n], 0,0,0);
  }

  #pragma unroll
  for (int m=0;m<2;m++){
    #pragma unroll
    for (int q=0;q<4;q++){
      int r = m0 + w*32 + m*16 + ((lane>>4)<<2) + q;
      float qv = (MODE>=2) ? q2[r] : 0.f;
      float tv = (MODE==3) ? thr[r] : 0.f;
      #pragma unroll
      for (int n=0;n<8;n++){
        int c = n0 + n*16 + (lane&15);
        float v = acc[m][n][q];
        if (MODE==2){
          if (c<Ndim){ float d2 = fmaxf(qv+m2[c]-2.f*v, 0.f); Cf[(long)r*ldc + c] = d2; }
        } else {
          if (c<Ndim){
            float d2 = fmaxf(qv+m2[c]-2.f*v, 0.f);
            if (d2 <= tv){
              int p = atomicAdd(&cnt[r],1);
              if (p < CAP){ cand_d2[(long)r*CAP+p]=d2; cand_idx[(long)r*CAP+p]=c; }
            }
          }
        }
      }
    }
  }
}

// ============ unified bf16 A@B^T MFMA GEMM, 128x128x32 tile, 4 waves (projection GEMMs) ============
// MODE 0: C f32 = relu(acc + bias)         (gate hidden)
// MODE 1: C bf16 = acc + bias              (qp / u / ctx2)
// MODE 4: ctx = acc + bias; out2 = bf16(ctx); Cf f32 = qsrc + ctx  (Wo epilogue)
template<int MODE>
__global__ __launch_bounds__(256)
void gemm_uni(const u16* __restrict__ A, int lda, long az,
              const u16* __restrict__ Bm, int ldb, long bz,
              int Ndim, int Kdim,
              float* __restrict__ Cf, u16* __restrict__ Cb, int ldc, long cz,
              const float* __restrict__ bias, long biasz,
              const float* __restrict__ qsrc, u16* __restrict__ out2, int ldo2)
{
  const int m0 = blockIdx.x*128, n0 = blockIdx.y*128, z = blockIdx.z;
  A += (long)z*az; Bm += (long)z*bz;

  const int t = threadIdx.x;
  const int lane = t & 63, wid = t >> 6;
  __shared__ u16 As[2][128*32], Bs[2][128*32];
  f32x4 acc[4][4];
  #pragma unroll
  for (int m=0;m<4;m++)
    #pragma unroll
    for (int n=0;n<4;n++) acc[m][n] = f32x4{0.f,0.f,0.f,0.f};

  const int wr = (wid>>1)*64, wc = (wid&1)*64;
  const int sr = t>>2, sc4 = t&3;
  const int r0 = sr, r1 = sr+64;
  const int sl0 = (sc4 ^ ((r0>>1)&3))*8, sl1 = (sc4 ^ ((r1>>1)&3))*8;
  int jb0 = n0+r0; if (jb0>=Ndim) jb0=Ndim-1;
  int jb1 = n0+r1; if (jb1>=Ndim) jb1=Ndim-1;
  const u16* pa0 = &A[(long)(m0+r0)*lda + sc4*8];
  const u16* pa1 = &A[(long)(m0+r1)*lda + sc4*8];
  const u16* pb0 = &Bm[(long)jb0*ldb + sc4*8];
  const u16* pb1 = &Bm[(long)jb1*ldb + sc4*8];

  uint4 pA0,pA1,pB0,pB1, qA0,qA1,qB0,qB1;
  #define LOADG(S, K0) { S##A0 = *(const uint4*)(pa0+(K0)); S##A1 = *(const uint4*)(pa1+(K0)); \
                         S##B0 = *(const uint4*)(pb0+(K0)); S##B1 = *(const uint4*)(pb1+(K0)); }
  #define STORELDS(BUF, S) { *(uint4*)&As[BUF][r0*32+sl0] = S##A0; *(uint4*)&As[BUF][r1*32+sl1] = S##A1; \
                             *(uint4*)&Bs[BUF][r0*32+sl0] = S##B0; *(uint4*)&Bs[BUF][r1*32+sl1] = S##B1; }

  auto compute = [&](const u16* __restrict__ Ab, const u16* __restrict__ Bb){
    bf16x8 af[4], bfr[4];
    #pragma unroll
    for (int m=0;m<4;m++){
      int row = wr + m*16 + (lane&15);
      int slot = ((lane>>4) ^ ((row>>1)&3));
      af[m] = __builtin_bit_cast(bf16x8, *(const uint4*)&Ab[row*32 + slot*8]);
    }
    #pragma unroll
    for (int n=0;n<4;n++){
      int row = wc + n*16 + (lane&15);
      int slot = ((lane>>4) ^ ((row>>1)&3));
      bfr[n] = __builtin_bit_cast(bf16x8, *(const uint4*)&Bb[row*32 + slot*8]);
    }
    #pragma unroll
    for (int m=0;m<4;m++)
      #pragma unroll
      for (int n=0;n<4;n++)
        acc[m][n] = __builtin_amdgcn_mfma_f32_16x16x32_bf16(af[m], bfr[n], acc[m][n], 0,0,0);
  };

  const int nt = Kdim >> 5;
  LOADG(p, 0);
  if (nt > 1) LOADG(q, 32);
  #pragma unroll 1
  for (int ti=0; ti<nt; ti+=2){
    STORELDS(0, p);
    asm volatile("s_waitcnt lgkmcnt(0)" ::: "memory");
    __builtin_amdgcn_s_barrier();
    if (ti+2 < nt) LOADG(p, (ti+2)*32);
    compute(As[0], Bs[0]);
    if (ti+1 < nt){
      STORELDS(1, q);
      asm volatile("s_waitcnt lgkmcnt(0)" ::: "memory");
      __builtin_amdgcn_s_barrier();
      if (ti+3 < nt) LOADG(q, (ti+3)*32);
      compute(As[1], Bs[1]);
    }
  }
  #undef LOADG
  #undef STORELDS

  const float* bz_p = bias ? bias + (long)z*biasz : nullptr;
  #pragma unroll
  for (int m=0;m<4;m++){
    #pragma unroll
    for (int n=0;n<4;n++){
      #pragma unroll
      for (int q=0;q<4;q++){
        int r = m0 + wr + m*16 + ((lane>>4)<<2) + q;
        int c = n0 + wc + n*16 + (lane&15);
        float v = acc[m][n][q];
        if (MODE==0){
          if (c<Ndim){ if(bz_p) v += bz_p[c]; Cf[(long)r*ldc + (long)z*cz + c] = fmaxf(v,0.f); }
        } else if (MODE==1){
          if (c<Ndim){ if(bz_p) v += bz_p[c]; Cb[(long)r*ldc + (long)z*cz + c] = f2bf(v); }
        } else {
          if (c<Ndim){
            float ctx = v + (bz_p?bz_p[c]:0.f);
            out2[(long)r*ldo2 + c] = f2bf(ctx);
            Cf[(long)r*ldc + c] = qsrc[(long)r*ND+c] + ctx;   // enhanced, f32
          }
        }
      }
    }
  }
}

// ---------------- per-query threshold: per-wave bisection for 25th-smallest, min over waves ----------------
__global__ __launch_bounds__(256) void find_thr(const float* __restrict__ d2s, float* __restrict__ thr){
  int b = blockIdx.x, w = threadIdx.x>>6, l = threadIdx.x&63;
  const float4* base = (const float4*)(d2s + (long)b*SAMP + w*1024);
  float v[16];
  #pragma unroll
  for (int j=0;j<4;j++){
    float4 q = base[l*4+j];
    v[j*4]=q.x; v[j*4+1]=q.y; v[j*4+2]=q.z; v[j*4+3]=q.w;
  }
  u32 lo=0, hi=0x7f7fffffu;
  for (int it=0; it<28; ++it){
    u32 mid = (lo+hi)>>1;
    float fm = __builtin_bit_cast(float, mid);
    int c=0;
    #pragma unroll
    for (int j=0;j<16;j++) c += (v[j] <= fm) ? 1 : 0;
    #pragma unroll
    for (int o=32;o;o>>=1) c += __shfl_down(c,o);
    c = __shfl(c,0);
    if (c >= RSEL) hi = mid; else lo = mid+1;
  }
  __shared__ float wt[4];
  if (l==0) wt[w] = __builtin_bit_cast(float, hi);
  __syncthreads();
  if (threadIdx.x==0) thr[b] = fminf(fminf(wt[0],wt[1]), fminf(wt[2],wt[3]));
}

// ---------------- exact top-50: parallel rank-count over candidates ----------------
__global__ __launch_bounds__(256) void select50(const float* __restrict__ cand_d2, const int* __restrict__ cand_idx,
                                                const int* __restrict__ cnt, int* __restrict__ sel,
                                                float* __restrict__ dists, float* __restrict__ dsum){
  int b = blockIdx.x, t = threadIdx.x;
  __shared__ u64 arr[CAP];
  __shared__ float dS[NK];
  int n = cnt[b]; if (n > CAP) n = CAP;
  for (int i=t;i<n;i+=256){
    float d2 = fmaxf(cand_d2[(long)b*CAP+i],0.f);
    arr[i] = ((u64)__builtin_bit_cast(u32, d2)<<32) | (u32)cand_idx[(long)b*CAP+i];
  }
  if (t < NK){ dS[t]=0.f; sel[b*NK+t]=0; dists[b*NK+t]=0.f; }  // safety init (n<50 ~impossible)
  __syncthreads();
  for (int i=t;i<n;i+=256){
    u64 me = arr[i];
    int rank = 0;
    for (int j=0;j<n;j++) rank += (arr[j] < me) ? 1 : 0;   // unique keys -> unique ranks
    if (rank < NK){
      float d = sqrtf(__builtin_bit_cast(float, (u32)(me>>32)));
      sel[b*NK+rank] = (int)(u32)(me & 0xffffffffu);
      dists[b*NK+rank] = d;
      dS[rank] = d;
    }
  }
  __syncthreads();
  if (t==0){ float s=0.f; for (int r=0;r<NK;r++) s+=dS[r]; dsum[b]=s; }
}

__global__ void mean_kernel(const float* __restrict__ dsum, float* __restrict__ meanbuf){
  int t = threadIdx.x;
  float s=0.f; for (int i=t;i<NB;i+=256) s += dsum[i];
  __shared__ float red[256];
  red[t]=s; __syncthreads();
  #pragma unroll
  for (int st=128;st>0;st>>=1){ if(t<st) red[t]+=red[t+st]; __syncthreads(); }
  if (t==0){ float mean = red[0]/(float)(NB*NK); meanbuf[0]=mean; meanbuf[1]=1.f/mean; }
}

// ---------------- per-query attention: online softmax, bf16 gathers, + rag ----------------
__global__ __launch_bounds__(256) void attn_kernel(
    const int* __restrict__ sel, const u16* __restrict__ mkb,
    const u16* __restrict__ ub, const float* __restrict__ dists,
    const float* __restrict__ mvals, const float* __restrict__ meanbuf,
    u16* __restrict__ sb, float* __restrict__ out_rag)
{
  const int b = blockIdx.x, t = threadIdx.x;
  __shared__ u16 nkS[25*772];
  __shared__ u16 uS[8*772];
  __shared__ float sc[NH*32];
  __shared__ float mh[NH], dh[NH], scS[NH];
  __shared__ int selS[NK];
  if (t < NK) selS[t] = sel[b*NK+t];
  if (t >= 64 && t < 64+NH){ mh[t-64] = -1e30f; dh[t-64] = 0.f; }
  {
    const u32* src = (const u32*)&ub[(long)b*NH*ND];
    for (int i=t;i<NH*(ND/2);i+=256){
      int h = i/(ND/2), d = i%(ND/2);
      ((u32*)&uS[h*772])[d] = src[h*(ND/2)+d];
    }
  }
  float sacc[3][NH];
  #pragma unroll
  for (int j=0;j<3;j++)
    #pragma unroll
    for (int h=0;h<NH;h++) sacc[j][h]=0.f;
  const float rs = 0.10206207261596575f;  // 1/sqrt(96)

  for (int half=0; half<2; ++half){
    __syncthreads();
    for (int k=0;k<25;k++){
      const u32* src = (const u32*)&mkb[(long)selS[half*25+k]*ND];
      u32* dst = (u32*)&nkS[k*772];
      for (int i=t;i<ND/2;i+=256) dst[i] = src[i];
    }
    __syncthreads();
    if (t < 200){
      const u32* nr = (const u32*)&nkS[(t%25)*772];
      const u32* ur = (const u32*)&uS[(t/25)*772];
      float acc = 0.f;
      #pragma unroll 8
      for (int d=0; d<ND/2; d++){
        u32 a = nr[d], uu = ur[d];
        acc += bf2f((u16)a)*bf2f((u16)uu) + bf2f((u16)(a>>16))*bf2f((u16)(uu>>16));
      }
      sc[(t/25)*32 + (t%25)] = acc*rs;
    }
    __syncthreads();
    if (t < NH){
      float mn = mh[t];
      #pragma unroll
      for (int k=0;k<25;k++) mn = fmaxf(mn, sc[t*32+k]);
      float scale = __expf(mh[t]-mn);
      float d = dh[t]*scale;
      #pragma unroll
      for (int k=0;k<25;k++){ float e = __expf(sc[t*32+k]-mn); sc[t*32+k]=e; d+=e; }
      mh[t]=mn; dh[t]=d; scS[t]=scale;
    }
    __syncthreads();
    #pragma unroll
    for (int j=0;j<3;j++){
      int dd = t + j*256;
      #pragma unroll
      for (int h=0;h<NH;h++) sacc[j][h] *= scS[h];
      for (int k=0;k<25;k++){
        float nv = bf2f(nkS[k*772+dd]);
        float w0,w1,w2,w3,w4,w5,w6,w7;
        w0=sc[0*32+k]; w1=sc[1*32+k]; w2=sc[2*32+k]; w3=sc[3*32+k];
        w4=sc[4*32+k]; w5=sc[5*32+k]; w6=sc[6*32+k]; w7=sc[7*32+k];
        sacc[j][0]+=w0*nv; sacc[j][1]+=w1*nv; sacc[j][2]+=w2*nv; sacc[j][3]+=w3*nv;
        sacc[j][4]+=w4*nv; sacc[j][5]+=w5*nv; sacc[j][6]+=w6*nv; sacc[j][7]+=w7*nv;
      }
    }
  }
  float inv[NH];
  #pragma unroll
  for (int h=0;h<NH;h++) inv[h] = 1.f/dh[h];
  #pragma unroll
  for (int j=0;j<3;j++){
    int dd = t + j*256;
    #pragma unroll
    for (int h=0;h<NH;h++) sb[(long)b*NH*ND + h*ND + dd] = f2bf(sacc[j][h]*inv[h]);
  }
  if (t < 64){
    float num=0.f, den=0.f;
    if (t < NK){
      float d = dists[b*NK+t];
      float v = mvals[selS[t]];
      float e = __expf(-d*meanbuf[1]);
      num = e*v; den = e;
    }
    #pragma unroll
    for (int o=32;o;o>>=1){ num += __shfl_down(num,o); den += __shfl_down(den,o); }
    if (t==0) out_rag[b] = num/den;
  }
}

// ---------------- gate output ----------------
__global__ void gate2_kernel(const float* __restrict__ hg, const float* __restrict__ Wg2,
                             const float* __restrict__ bg2, float* __restrict__ outg){
  int b = blockIdx.x*4 + (threadIdx.x>>6);
  int l = threadIdx.x & 63;
  float s=0.f;
  for (int i=l;i<256;i+=64) s += hg[(long)b*256+i]*Wg2[i];
  #pragma unroll
  for (int o=32;o;o>>=1) s += __shfl_down(s,o);
  if (l==0) outg[b] = 1.f/(1.f+__expf(-(s+bg2[0])));
}

extern "C" void kernel_launch(void* const* d_in, const int* in_sizes, int n_in,
                              void* d_out, int out_size, void* d_ws, size_t ws_size,
                              hipStream_t stream){
  const float* query = (const float*)d_in[0];
  const float* mkeys = (const float*)d_in[1];
  const float* mvals = (const float*)d_in[2];
  const float* Wq  = (const float*)d_in[3];
  const float* bq  = (const float*)d_in[4];
  const float* Wk  = (const float*)d_in[5];
  const float* Wv  = (const float*)d_in[7];
  const float* bv  = (const float*)d_in[8];
  const float* Wo  = (const float*)d_in[9];
  const float* bo  = (const float*)d_in[10];
  const float* Wg1 = (const float*)d_in[11];
  const float* bg1 = (const float*)d_in[12];
  const float* Wg2 = (const float*)d_in[13];
  const float* bg2 = (const float*)d_in[14];
  float* out = (float*)d_out;           // f32: [enhanced B*768 | rag B | gate B]

  char* ws = (char*)d_ws;
  size_t off = 0;
  auto alloc = [&](size_t bytes)->char*{ char* p = ws + off; off += (bytes + 255) & ~(size_t)255; return p; };

  u16*   mkb   = (u16*)  alloc((size_t)NM*ND*2);
  u16*   qb    = (u16*)  alloc((size_t)NB*ND*2);
  u16*   comb  = (u16*)  alloc((size_t)NB*2*ND*2);
  float* q2    = (float*)alloc(NB*4);
  float* m2    = (float*)alloc(NM*4);
  u16*   wqb   = (u16*)  alloc((size_t)ND*ND*2);
  u16*   wkt   = (u16*)  alloc((size_t)ND*ND*2);
  u16*   wvb   = (u16*)  alloc((size_t)ND*ND*2);
  u16*   wob   = (u16*)  alloc((size_t)ND*ND*2);
  u16*   wg1b  = (u16*)  alloc((size_t)256*2*ND*2);
  float* d2s   = (float*)alloc((size_t)NB*SAMP*4);   // aliased below by cand arrays (d2s dead after find_thr)
  float* thr   = (float*)alloc(NB*4);
  int*   cnt   = (int*)  alloc(NB*4);
  int*   sel   = (int*)  alloc((size_t)NB*NK*4);
  float* dists = (float*)alloc((size_t)NB*NK*4);
  float* dsum  = (float*)alloc(NB*4);
  float* meanbuf=(float*)alloc(256);
  u16*   qpb   = (u16*)  alloc((size_t)NB*ND*2);
  u16*   ubuf  = (u16*)  alloc((size_t)NB*NH*ND*2);
  u16*   sbuf  = (u16*)  alloc((size_t)NB*NH*ND*2);
  u16*   ctx2b = (u16*)  alloc((size_t)NB*ND*2);
  float* hg    = (float*)alloc((size_t)NB*256*4);
  // alias: cand buffers live in d2s region (16.8MB; cand needs 8.4+8.4MB); stream-ordered safe
  float* cand_d2 = d2s;
  int*   cand_idx= (int*)(d2s + (size_t)NB*CAP);
  (void)ws_size; (void)in_sizes; (void)n_in; (void)out_size;

  // prep
  prep_query<<<NB/4, 256, 0, stream>>>(query, qb, q2, comb);
  prep_mk<<<NM/4, 256, 0, stream>>>(mkeys, mkb, m2);
  cvt_bf<<<(ND*ND+255)/256, 256, 0, stream>>>(Wq, wqb, ND*ND);
  cvt_bf<<<(ND*ND+255)/256, 256, 0, stream>>>(Wv, wvb, ND*ND);
  cvt_bf<<<(ND*ND+255)/256, 256, 0, stream>>>(Wo, wob, ND*ND);
  cvt_bf<<<(256*2*ND+255)/256, 256, 0, stream>>>(Wg1, wg1b, 256*2*ND);
  transpose_wk<<<(ND*ND+255)/256, 256, 0, stream>>>(Wk, wkt);

  // retrieval: sample -> threshold -> filtered candidates -> exact top-50
  // 1-D XCD-swizzled grids: bid = y%8 + 8*(x + 16*(y/8)); 16 M-tiles of 64 rows
  gemm64<2><<<512, 128, 0, stream>>>(qb,ND, mkb,ND, SAMP,ND,32,
      d2s,SAMP, q2,m2,nullptr, nullptr,nullptr,nullptr);
  find_thr<<<NB, 256, 0, stream>>>(d2s, thr);
  hipMemsetAsync(cnt, 0, NB*sizeof(int), stream);
  gemm64<3><<<6272, 128, 0, stream>>>(qb,ND, mkb,ND, NM,ND,391,
      nullptr,0, q2,m2,thr, cand_d2,cand_idx,cnt);
  select50<<<NB, 256, 0, stream>>>(cand_d2, cand_idx, cnt, sel, dists, dsum);
  mean_kernel<<<1, 256, 0, stream>>>(dsum, meanbuf);

  // q-projection, then u[b,h,:] = Wk_h^T @ q_h  (collapses K-projection)
  gemm_uni<1><<<dim3(NB/128, ND/128, 1), 256, 0, stream>>>(qb,ND,0, wqb,ND,0, ND,ND,
      nullptr,qpb,ND,0, bq,0, nullptr,nullptr,0);
  gemm_uni<1><<<dim3(NB/128, ND/128, NH), 256, 0, stream>>>(qpb,ND,96, wkt,96,(long)ND*96, ND,96,
      nullptr,ubuf,NH*ND,ND, nullptr,0, nullptr,nullptr,0);

  // attention scores/softmax/weighted-neighbor-sum + rag prediction
  attn_kernel<<<NB, 256, 0, stream>>>(sel, mkb, ubuf, dists, mvals, meanbuf, sbuf, out + (size_t)NB*ND);

  // ctx2[b,h*96+hd] = Wv_h @ s_h + bv   (collapses V-projection; exact since sum(attn)=1)
  gemm_uni<1><<<dim3(NB/128, 1, NH), 256, 0, stream>>>(sbuf,NH*ND,ND, wvb,ND,(long)96*ND, 96,ND,
      nullptr,ctx2b,ND,96, bv,96, nullptr,nullptr,0);

  // context = ctx2 @ Wo^T + bo; enhanced (f32) = query + context -> out; context -> combined[:,768:]
  gemm_uni<4><<<dim3(NB/128, ND/128, 1), 256, 0, stream>>>(ctx2b,ND,0, wob,ND,0, ND,ND,
      out,nullptr,ND,0, bo,0, query, comb+ND, 2*ND);

  // gate MLP
  gemm_uni<0><<<dim3(NB/128, 2, 1), 256, 0, stream>>>(comb,2*ND,0, wg1b,2*ND,0, 256,2*ND,
      hg,nullptr,256,0, bg1,0, nullptr,nullptr,0);
  gate2_kernel<<<NB/4, 256, 0, stream>>>(hg, Wg2, bg2, out + (size_t)NB*ND + NB);
}

// Round 8
// 793.355 us; speedup vs baseline: 1.4720x; 1.0486x over previous
//
#include <hip/hip_runtime.h>

typedef unsigned int u32;
typedef unsigned short u16;
typedef unsigned char u8;
typedef signed char s8;
typedef unsigned long long u64;
typedef __bf16 bf16x8 __attribute__((ext_vector_type(8)));
typedef float f32x4 __attribute__((ext_vector_type(4)));
typedef int i32x4 __attribute__((ext_vector_type(4)));

#define DEVI __device__ __forceinline__

DEVI u16 f2bf(float x){ u32 u = __builtin_bit_cast(u32, x); return (u16)((u + 0x7fffu + ((u>>16)&1u)) >> 16); }
DEVI float bf2f(u16 h){ return __builtin_bit_cast(float, ((u32)h)<<16); }
DEVI u32 qz(float x){ int i = (int)rintf(x*25.4f); i = i>127?127:(i<-127?-127:i); return (u32)(u8)(s8)i; }

// constants
#define NB 1024
#define ND 768
#define NM 50000
#define NK 50
#define NH 8
#define SAMP 4096
#define RSEL 25
#define CAP 2048
#define S22 0.0031000062f   // 2*(5/127)^2 : i8 scale^2 for the -2*q.m term

// ---------------- prep: wave-per-row f32 -> i8 (+ norms) ----------------
__global__ __launch_bounds__(256) void prep_mk(const float* __restrict__ src, s8* __restrict__ mi8,
                                               float* __restrict__ nrm2){
  int r = blockIdx.x*4 + (threadIdx.x>>6);
  int l = threadIdx.x & 63;
  const float4* s4 = (const float4*)(src + (long)r*ND);
  u32* di = (u32*)(mi8 + (long)r*ND);
  float ss = 0.f;
  #pragma unroll
  for (int j=0;j<3;j++){
    float4 v = s4[l + j*64];
    ss += v.x*v.x + v.y*v.y + v.z*v.z + v.w*v.w;
    di[l+j*64] = qz(v.x) | (qz(v.y)<<8) | (qz(v.z)<<16) | (qz(v.w)<<24);
  }
  #pragma unroll
  for (int o=32;o;o>>=1) ss += __shfl_down(ss,o);
  if (l==0) nrm2[r]=ss;
}

__global__ __launch_bounds__(256) void prep_query(const float* __restrict__ src, u16* __restrict__ qb,
                                                  float* __restrict__ q2, u16* __restrict__ comb,
                                                  s8* __restrict__ qi8){
  int r = blockIdx.x*4 + (threadIdx.x>>6);
  int l = threadIdx.x & 63;
  const float4* s4 = (const float4*)(src + (long)r*ND);
  u32* dq = (u32*)(qb + (long)r*ND);
  u32* dc = (u32*)(comb + (long)r*2*ND);
  u32* di = (u32*)(qi8 + (long)r*ND);
  float ss = 0.f;
  #pragma unroll
  for (int j=0;j<3;j++){
    float4 v = s4[l + j*64];
    ss += v.x*v.x + v.y*v.y + v.z*v.z + v.w*v.w;
    u32 p0 = ((u32)f2bf(v.y)<<16) | f2bf(v.x);
    u32 p1 = ((u32)f2bf(v.w)<<16) | f2bf(v.z);
    dq[(l+j*64)*2]=p0; dq[(l+j*64)*2+1]=p1;
    dc[(l+j*64)*2]=p0; dc[(l+j*64)*2+1]=p1;
    di[l+j*64] = qz(v.x) | (qz(v.y)<<8) | (qz(v.z)<<16) | (qz(v.w)<<24);
  }
  #pragma unroll
  for (int o=32;o;o>>=1) ss += __shfl_down(ss,o);
  if (l==0) q2[r]=ss;
}

__global__ void cvt_bf(const float* __restrict__ s, u16* __restrict__ d, int n){
  int i = blockIdx.x*256 + threadIdx.x;
  if (i<n) d[i] = f2bf(s[i]);
}

// wkt[h][d][hd] = Wk[h*96+hd][d]
__global__ void transpose_wk(const float* __restrict__ Wk, u16* __restrict__ wkt){
  int i = blockIdx.x*256 + threadIdx.x;
  if (i >= NH*ND*96) return;
  int h = i / (ND*96); int rem = i % (ND*96); int d = rem / 96; int hd = rem % 96;
  wkt[i] = f2bf(Wk[(long)(h*96+hd)*ND + d]);
}

// ============ i8 retrieval GEMM: 64x128 tile, K-step 64 (12 serial steps), 2 waves/block ============
// Same proven 2-barrier structure/LDS-swizzle as the bf16 gemm64 (byte-identical tiling: a row's
// K-step is 64B = 4x16B chunks), but mfma_i32_16x16x64_i8 halves serial K-steps AND staged bytes.
// d2 = q2[r] + m2[c] - 2*s^2*dot_i8  (exact f32 norms; i8 cross term, sigma ~= bf16 path's).
// 1-D XCD-swizzled grid. MODE 2: write d2. MODE 3: d2 <= thr[r] -> atomic append.
template<int MODE>
__global__ __launch_bounds__(128)
void gemm64_i8(const s8* __restrict__ A, int lda,
               const s8* __restrict__ Bm, int ldb,
               int Ndim, int Kbytes, int ny,
               float* __restrict__ Cf, int ldc,
               const float* __restrict__ q2, const float* __restrict__ m2, const float* __restrict__ thr,
               float* __restrict__ cand_d2, int* __restrict__ cand_idx, int* __restrict__ cnt)
{
  const int cxcd = blockIdx.x & 7; const int j = blockIdx.x >> 3;
  const int xt = j & 15, yhi = j >> 4;
  const int y = yhi*8 + cxcd;
  if (y >= ny) return;
  const int m0 = xt*64, n0 = y*128;

  const int t = threadIdx.x;
  const int lane = t & 63, w = t >> 6;
  __shared__ u8 As[64*64], Bs[128*64];
  i32x4 acc[2][8];
  #pragma unroll
  for (int m=0;m<2;m++)
    #pragma unroll
    for (int n=0;n<8;n++) acc[m][n] = i32x4{0,0,0,0};

  // staging: 128 threads; A 64 rows x 4 chunks (2/thread), B 128 rows x 4 chunks (4/thread)
  const int ra = t>>1, c0 = (t&1)*2;
  const int rb1 = ra+64;
  const int sw = (ra>>1)&3;
  const int s0 = ((c0  )^sw)*16, s1 = ((c0+1)^sw)*16;  // XOR-swizzled 16B chunk slots
  int jb0 = n0+ra;  if (jb0>=Ndim) jb0=Ndim-1;
  int jb1 = n0+rb1; if (jb1>=Ndim) jb1=Ndim-1;
  const s8* pa  = &A[(long)(m0+ra)*lda + c0*16];
  const s8* pb0 = &Bm[(long)jb0*ldb + c0*16];
  const s8* pb1 = &Bm[(long)jb1*ldb + c0*16];

  for (int k0=0; k0<Kbytes; k0+=64){
    __syncthreads();
    uint4 a0  = *(const uint4*)(pa  + k0);
    uint4 a1  = *(const uint4*)(pa  + k0 + 16);
    uint4 b00 = *(const uint4*)(pb0 + k0);
    uint4 b01 = *(const uint4*)(pb0 + k0 + 16);
    uint4 b10 = *(const uint4*)(pb1 + k0);
    uint4 b11 = *(const uint4*)(pb1 + k0 + 16);
    *(uint4*)&As[ra*64 + s0]  = a0;
    *(uint4*)&As[ra*64 + s1]  = a1;
    *(uint4*)&Bs[ra*64 + s0]  = b00;
    *(uint4*)&Bs[ra*64 + s1]  = b01;
    *(uint4*)&Bs[rb1*64 + s0] = b10;
    *(uint4*)&Bs[rb1*64 + s1] = b11;
    __syncthreads();
    i32x4 af[2], bfr[8];
    #pragma unroll
    for (int m=0;m<2;m++){
      int row = w*32 + m*16 + (lane&15);
      int slot = ((lane>>4) ^ ((row>>1)&3));
      af[m] = __builtin_bit_cast(i32x4, *(const uint4*)&As[row*64 + slot*16]);
    }
    #pragma unroll
    for (int n=0;n<8;n++){
      int row = n*16 + (lane&15);
      int slot = ((lane>>4) ^ ((row>>1)&3));
      bfr[n] = __builtin_bit_cast(i32x4, *(const uint4*)&Bs[row*64 + slot*16]);
    }
    #pragma unroll
    for (int m=0;m<2;m++)
      #pragma unroll
      for (int n=0;n<8;n++)
        acc[m][n] = __builtin_amdgcn_mfma_i32_16x16x64_i8(af[m], bfr[n], acc[m][n], 0,0,0);
  }

  #pragma unroll
  for (int m=0;m<2;m++){
    #pragma unroll
    for (int q=0;q<4;q++){
      int r = m0 + w*32 + m*16 + ((lane>>4)<<2) + q;
      float qv = q2[r];
      float tv = (MODE==3) ? thr[r] : 0.f;
      #pragma unroll
      for (int n=0;n<8;n++){
        int c = n0 + n*16 + (lane&15);
        float v = S22 * (float)acc[m][n][q];
        if (MODE==2){
          if (c<Ndim){ float d2 = fmaxf(qv+m2[c]-v, 0.f); Cf[(long)r*ldc + c] = d2; }
        } else {
          if (c<Ndim){
            float d2 = fmaxf(qv+m2[c]-v, 0.f);
            if (d2 <= tv){
              int p = atomicAdd(&cnt[r],1);
              if (p < CAP){ cand_d2[(long)r*CAP+p]=d2; cand_idx[(long)r*CAP+p]=c; }
            }
          }
        }
      }
    }
  }
}

// ============ unified bf16 A@B^T MFMA GEMM, 128x128x32 tile, 4 waves (projection GEMMs) ============
// MODE 0: C f32 = relu(acc + bias)         (gate hidden)
// MODE 1: C bf16 = acc + bias              (qp / u / ctx2)
// MODE 4: ctx = acc + bias; out2 = bf16(ctx); Cf f32 = qsrc + ctx  (Wo epilogue)
template<int MODE>
__global__ __launch_bounds__(256)
void gemm_uni(const u16* __restrict__ A, int lda, long az,
              const u16* __restrict__ Bm, int ldb, long bz,
              int Ndim, int Kdim,
              float* __restrict__ Cf, u16* __restrict__ Cb, int ldc, long cz,
              const float* __restrict__ bias, long biasz,
              const float* __restrict__ qsrc, u16* __restrict__ out2, int ldo2)
{
  const int m0 = blockIdx.x*128, n0 = blockIdx.y*128, z = blockIdx.z;
  A += (long)z*az; Bm += (long)z*bz;

  const int t = threadIdx.x;
  const int lane = t & 63, wid = t >> 6;
  __shared__ u16 As[2][128*32], Bs[2][128*32];
  f32x4 acc[4][4];
  #pragma unroll
  for (int m=0;m<4;m++)
    #pragma unroll
    for (int n=0;n<4;n++) acc[m][n] = f32x4{0.f,0.f,0.f,0.f};

  const int wr = (wid>>1)*64, wc = (wid&1)*64;
  const int sr = t>>2, sc4 = t&3;
  const int r0 = sr, r1 = sr+64;
  const int sl0 = (sc4 ^ ((r0>>1)&3))*8, sl1 = (sc4 ^ ((r1>>1)&3))*8;
  int jb0 = n0+r0; if (jb0>=Ndim) jb0=Ndim-1;
  int jb1 = n0+r1; if (jb1>=Ndim) jb1=Ndim-1;
  const u16* pa0 = &A[(long)(m0+r0)*lda + sc4*8];
  const u16* pa1 = &A[(long)(m0+r1)*lda + sc4*8];
  const u16* pb0 = &Bm[(long)jb0*ldb + sc4*8];
  const u16* pb1 = &Bm[(long)jb1*ldb + sc4*8];

  uint4 pA0,pA1,pB0,pB1, qA0,qA1,qB0,qB1;
  #define LOADG(S, K0) { S##A0 = *(const uint4*)(pa0+(K0)); S##A1 = *(const uint4*)(pa1+(K0)); \
                         S##B0 = *(const uint4*)(pb0+(K0)); S##B1 = *(const uint4*)(pb1+(K0)); }
  #define STORELDS(BUF, S) { *(uint4*)&As[BUF][r0*32+sl0] = S##A0; *(uint4*)&As[BUF][r1*32+sl1] = S##A1; \
                             *(uint4*)&Bs[BUF][r0*32+sl0] = S##B0; *(uint4*)&Bs[BUF][r1*32+sl1] = S##B1; }

  auto compute = [&](const u16* __restrict__ Ab, const u16* __restrict__ Bb){
    bf16x8 af[4], bfr[4];
    #pragma unroll
    for (int m=0;m<4;m++){
      int row = wr + m*16 + (lane&15);
      int slot = ((lane>>4) ^ ((row>>1)&3));
      af[m] = __builtin_bit_cast(bf16x8, *(const uint4*)&Ab[row*32 + slot*8]);
    }
    #pragma unroll
    for (int n=0;n<4;n++){
      int row = wc + n*16 + (lane&15);
      int slot = ((lane>>4) ^ ((row>>1)&3));
      bfr[n] = __builtin_bit_cast(bf16x8, *(const uint4*)&Bb[row*32 + slot*8]);
    }
    #pragma unroll
    for (int m=0;m<4;m++)
      #pragma unroll
      for (int n=0;n<4;n++)
        acc[m][n] = __builtin_amdgcn_mfma_f32_16x16x32_bf16(af[m], bfr[n], acc[m][n], 0,0,0);
  };

  const int nt = Kdim >> 5;
  LOADG(p, 0);
  if (nt > 1) LOADG(q, 32);
  #pragma unroll 1
  for (int ti=0; ti<nt; ti+=2){
    STORELDS(0, p);
    asm volatile("s_waitcnt lgkmcnt(0)" ::: "memory");
    __builtin_amdgcn_s_barrier();
    if (ti+2 < nt) LOADG(p, (ti+2)*32);
    compute(As[0], Bs[0]);
    if (ti+1 < nt){
      STORELDS(1, q);
      asm volatile("s_waitcnt lgkmcnt(0)" ::: "memory");
      __builtin_amdgcn_s_barrier();
      if (ti+3 < nt) LOADG(q, (ti+3)*32);
      compute(As[1], Bs[1]);
    }
  }
  #undef LOADG
  #undef STORELDS

  const float* bz_p = bias ? bias + (long)z*biasz : nullptr;
  #pragma unroll
  for (int m=0;m<4;m++){
    #pragma unroll
    for (int n=0;n<4;n++){
      #pragma unroll
      for (int q=0;q<4;q++){
        int r = m0 + wr + m*16 + ((lane>>4)<<2) + q;
        int c = n0 + wc + n*16 + (lane&15);
        float v = acc[m][n][q];
        if (MODE==0){
          if (c<Ndim){ if(bz_p) v += bz_p[c]; Cf[(long)r*ldc + (long)z*cz + c] = fmaxf(v,0.f); }
        } else if (MODE==1){
          if (c<Ndim){ if(bz_p) v += bz_p[c]; Cb[(long)r*ldc + (long)z*cz + c] = f2bf(v); }
        } else {
          if (c<Ndim){
            float ctx = v + (bz_p?bz_p[c]:0.f);
            out2[(long)r*ldo2 + c] = f2bf(ctx);
            Cf[(long)r*ldc + c] = qsrc[(long)r*ND+c] + ctx;   // enhanced, f32
          }
        }
      }
    }
  }
}

// ---------------- per-query threshold: per-wave bisection for 25th-smallest, min over waves ----------------
__global__ __launch_bounds__(256) void find_thr(const float* __restrict__ d2s, float* __restrict__ thr){
  int b = blockIdx.x, w = threadIdx.x>>6, l = threadIdx.x&63;
  const float4* base = (const float4*)(d2s + (long)b*SAMP + w*1024);
  float v[16];
  #pragma unroll
  for (int j=0;j<4;j++){
    float4 q = base[l*4+j];
    v[j*4]=q.x; v[j*4+1]=q.y; v[j*4+2]=q.z; v[j*4+3]=q.w;
  }
  u32 lo=0, hi=0x7f7fffffu;
  for (int it=0; it<28; ++it){
    u32 mid = (lo+hi)>>1;
    float fm = __builtin_bit_cast(float, mid);
    int c=0;
    #pragma unroll
    for (int j=0;j<16;j++) c += (v[j] <= fm) ? 1 : 0;
    #pragma unroll
    for (int o=32;o;o>>=1) c += __shfl_down(c,o);
    c = __shfl(c,0);
    if (c >= RSEL) hi = mid; else lo = mid+1;
  }
  __shared__ float wt[4];
  if (l==0) wt[w] = __builtin_bit_cast(float, hi);
  __syncthreads();
  if (threadIdx.x==0) thr[b] = fminf(fminf(wt[0],wt[1]), fminf(wt[2],wt[3]));
}

// ---------------- exact top-50: parallel rank-count over candidates ----------------
__global__ __launch_bounds__(256) void select50(const float* __restrict__ cand_d2, const int* __restrict__ cand_idx,
                                                const int* __restrict__ cnt, int* __restrict__ sel,
                                                float* __restrict__ dists, float* __restrict__ dsum){
  int b = blockIdx.x, t = threadIdx.x;
  __shared__ u64 arr[CAP];
  __shared__ float dS[NK];
  int n = cnt[b]; if (n > CAP) n = CAP;
  for (int i=t;i<n;i+=256){
    float d2 = fmaxf(cand_d2[(long)b*CAP+i],0.f);
    arr[i] = ((u64)__builtin_bit_cast(u32, d2)<<32) | (u32)cand_idx[(long)b*CAP+i];
  }
  if (t < NK){ dS[t]=0.f; sel[b*NK+t]=0; dists[b*NK+t]=0.f; }  // safety init (n<50 ~impossible)
  __syncthreads();
  for (int i=t;i<n;i+=256){
    u64 me = arr[i];
    int rank = 0;
    for (int j=0;j<n;j++) rank += (arr[j] < me) ? 1 : 0;   // unique keys -> unique ranks
    if (rank < NK){
      float d = sqrtf(__builtin_bit_cast(float, (u32)(me>>32)));
      sel[b*NK+rank] = (int)(u32)(me & 0xffffffffu);
      dists[b*NK+rank] = d;
      dS[rank] = d;
    }
  }
  __syncthreads();
  if (t==0){ float s=0.f; for (int r=0;r<NK;r++) s+=dS[r]; dsum[b]=s; }
}

__global__ void mean_kernel(const float* __restrict__ dsum, float* __restrict__ meanbuf){
  int t = threadIdx.x;
  float s=0.f; for (int i=t;i<NB;i+=256) s += dsum[i];
  __shared__ float red[256];
  red[t]=s; __syncthreads();
  #pragma unroll
  for (int st=128;st>0;st>>=1){ if(t<st) red[t]+=red[t+st]; __syncthreads(); }
  if (t==0){ float mean = red[0]/(float)(NB*NK); meanbuf[0]=mean; meanbuf[1]=1.f/mean; }
}

// ---------------- per-query attention: online softmax, f32-source gathers, + rag ----------------
__global__ __launch_bounds__(256) void attn_kernel(
    const int* __restrict__ sel, const float* __restrict__ mk,
    const u16* __restrict__ ub, const float* __restrict__ dists,
    const float* __restrict__ mvals, const float* __restrict__ meanbuf,
    u16* __restrict__ sb, float* __restrict__ out_rag)
{
  const int b = blockIdx.x, t = threadIdx.x;
  __shared__ u16 nkS[25*772];
  __shared__ u16 uS[8*772];
  __shared__ float sc[NH*32];
  __shared__ float mh[NH], dh[NH], scS[NH];
  __shared__ int selS[NK];
  if (t < NK) selS[t] = sel[b*NK+t];
  if (t >= 64 && t < 64+NH){ mh[t-64] = -1e30f; dh[t-64] = 0.f; }
  {
    const u32* src = (const u32*)&ub[(long)b*NH*ND];
    for (int i=t;i<NH*(ND/2);i+=256){
      int h = i/(ND/2), d = i%(ND/2);
      ((u32*)&uS[h*772])[d] = src[h*(ND/2)+d];
    }
  }
  float sacc[3][NH];
  #pragma unroll
  for (int j=0;j<3;j++)
    #pragma unroll
    for (int h=0;h<NH;h++) sacc[j][h]=0.f;
  const float rs = 0.10206207261596575f;  // 1/sqrt(96)

  for (int half=0; half<2; ++half){
    __syncthreads();
    for (int k=0;k<25;k++){
      const float* src = &mk[(long)selS[half*25+k]*ND];
      for (int i=t;i<ND;i+=256) nkS[k*772+i] = f2bf(src[i]);
    }
    __syncthreads();
    if (t < 200){
      const u32* nr = (const u32*)&nkS[(t%25)*772];
      const u32* ur = (const u32*)&uS[(t/25)*772];
      float acc = 0.f;
      #pragma unroll 8
      for (int d=0; d<ND/2; d++){
        u32 a = nr[d], uu = ur[d];
        acc += bf2f((u16)a)*bf2f((u16)uu) + bf2f((u16)(a>>16))*bf2f((u16)(uu>>16));
      }
      sc[(t/25)*32 + (t%25)] = acc*rs;
    }
    __syncthreads();
    if (t < NH){
      float mn = mh[t];
      #pragma unroll
      for (int k=0;k<25;k++) mn = fmaxf(mn, sc[t*32+k]);
      float scale = __expf(mh[t]-mn);
      float d = dh[t]*scale;
      #pragma unroll
      for (int k=0;k<25;k++){ float e = __expf(sc[t*32+k]-mn); sc[t*32+k]=e; d+=e; }
      mh[t]=mn; dh[t]=d; scS[t]=scale;
    }
    __syncthreads();
    #pragma unroll
    for (int j=0;j<3;j++){
      int dd = t + j*256;
      #pragma unroll
      for (int h=0;h<NH;h++) sacc[j][h] *= scS[h];
      for (int k=0;k<25;k++){
        float nv = bf2f(nkS[k*772+dd]);
        float w0,w1,w2,w3,w4,w5,w6,w7;
        w0=sc[0*32+k]; w1=sc[1*32+k]; w2=sc[2*32+k]; w3=sc[3*32+k];
        w4=sc[4*32+k]; w5=sc[5*32+k]; w6=sc[6*32+k]; w7=sc[7*32+k];
        sacc[j][0]+=w0*nv; sacc[j][1]+=w1*nv; sacc[j][2]+=w2*nv; sacc[j][3]+=w3*nv;
        sacc[j][4]+=w4*nv; sacc[j][5]+=w5*nv; sacc[j][6]+=w6*nv; sacc[j][7]+=w7*nv;
      }
    }
  }
  float inv[NH];
  #pragma unroll
  for (int h=0;h<NH;h++) inv[h] = 1.f/dh[h];
  #pragma unroll
  for (int j=0;j<3;j++){
    int dd = t + j*256;
    #pragma unroll
    for (int h=0;h<NH;h++) sb[(long)b*NH*ND + h*ND + dd] = f2bf(sacc[j][h]*inv[h]);
  }
  if (t < 64){
    float num=0.f, den=0.f;
    if (t < NK){
      float d = dists[b*NK+t];
      float v = mvals[selS[t]];
      float e = __expf(-d*meanbuf[1]);
      num = e*v; den = e;
    }
    #pragma unroll
    for (int o=32;o;o>>=1){ num += __shfl_down(num,o); den += __shfl_down(den,o); }
    if (t==0) out_rag[b] = num/den;
  }
}

// ---------------- gate output ----------------
__global__ void gate2_kernel(const float* __restrict__ hg, const float* __restrict__ Wg2,
                             const float* __restrict__ bg2, float* __restrict__ outg){
  int b = blockIdx.x*4 + (threadIdx.x>>6);
  int l = threadIdx.x & 63;
  float s=0.f;
  for (int i=l;i<256;i+=64) s += hg[(long)b*256+i]*Wg2[i];
  #pragma unroll
  for (int o=32;o;o>>=1) s += __shfl_down(s,o);
  if (l==0) outg[b] = 1.f/(1.f+__expf(-(s+bg2[0])));
}

extern "C" void kernel_launch(void* const* d_in, const int* in_sizes, int n_in,
                              void* d_out, int out_size, void* d_ws, size_t ws_size,
                              hipStream_t stream){
  const float* query = (const float*)d_in[0];
  const float* mkeys = (const float*)d_in[1];
  const float* mvals = (const float*)d_in[2];
  const float* Wq  = (const float*)d_in[3];
  const float* bq  = (const float*)d_in[4];
  const float* Wk  = (const float*)d_in[5];
  const float* Wv  = (const float*)d_in[7];
  const float* bv  = (const float*)d_in[8];
  const float* Wo  = (const float*)d_in[9];
  const float* bo  = (const float*)d_in[10];
  const float* Wg1 = (const float*)d_in[11];
  const float* bg1 = (const float*)d_in[12];
  const float* Wg2 = (const float*)d_in[13];
  const float* bg2 = (const float*)d_in[14];
  float* out = (float*)d_out;           // f32: [enhanced B*768 | rag B | gate B]

  char* ws = (char*)d_ws;
  size_t off = 0;
  auto alloc = [&](size_t bytes)->char*{ char* p = ws + off; off += (bytes + 255) & ~(size_t)255; return p; };

  s8*    mi8   = (s8*)   alloc((size_t)NM*ND);
  s8*    qi8   = (s8*)   alloc((size_t)NB*ND);
  u16*   qb    = (u16*)  alloc((size_t)NB*ND*2);
  u16*   comb  = (u16*)  alloc((size_t)NB*2*ND*2);
  float* q2    = (float*)alloc(NB*4);
  float* m2    = (float*)alloc(NM*4);
  u16*   wqb   = (u16*)  alloc((size_t)ND*ND*2);
  u16*   wkt   = (u16*)  alloc((size_t)ND*ND*2);
  u16*   wvb   = (u16*)  alloc((size_t)ND*ND*2);
  u16*   wob   = (u16*)  alloc((size_t)ND*ND*2);
  u16*   wg1b  = (u16*)  alloc((size_t)256*2*ND*2);
  float* d2s   = (float*)alloc((size_t)NB*SAMP*4);   // aliased below by cand arrays (d2s dead after find_thr)
  float* thr   = (float*)alloc(NB*4);
  int*   cnt   = (int*)  alloc(NB*4);
  int*   sel   = (int*)  alloc((size_t)NB*NK*4);
  float* dists = (float*)alloc((size_t)NB*NK*4);
  float* dsum  = (float*)alloc(NB*4);
  float* meanbuf=(float*)alloc(256);
  u16*   qpb   = (u16*)  alloc((size_t)NB*ND*2);
  u16*   ubuf  = (u16*)  alloc((size_t)NB*NH*ND*2);
  u16*   sbuf  = (u16*)  alloc((size_t)NB*NH*ND*2);
  u16*   ctx2b = (u16*)  alloc((size_t)NB*ND*2);
  float* hg    = (float*)alloc((size_t)NB*256*4);
  // alias: cand buffers live in d2s region (16.8MB; cand needs 8.4+8.4MB); stream-ordered safe
  float* cand_d2 = d2s;
  int*   cand_idx= (int*)(d2s + (size_t)NB*CAP);
  (void)ws_size; (void)in_sizes; (void)n_in; (void)out_size;

  // prep
  prep_query<<<NB/4, 256, 0, stream>>>(query, qb, q2, comb, qi8);
  prep_mk<<<NM/4, 256, 0, stream>>>(mkeys, mi8, m2);
  cvt_bf<<<(ND*ND+255)/256, 256, 0, stream>>>(Wq, wqb, ND*ND);
  cvt_bf<<<(ND*ND+255)/256, 256, 0, stream>>>(Wv, wvb, ND*ND);
  cvt_bf<<<(ND*ND+255)/256, 256, 0, stream>>>(Wo, wob, ND*ND);
  cvt_bf<<<(256*2*ND+255)/256, 256, 0, stream>>>(Wg1, wg1b, 256*2*ND);
  transpose_wk<<<(ND*ND+255)/256, 256, 0, stream>>>(Wk, wkt);

  // retrieval: i8 sample -> threshold -> i8 filtered candidates -> exact top-50
  gemm64_i8<2><<<512, 128, 0, stream>>>(qi8,ND, mi8,ND, SAMP,ND,32,
      d2s,SAMP, q2,m2,nullptr, nullptr,nullptr,nullptr);
  find_thr<<<NB, 256, 0, stream>>>(d2s, thr);
  hipMemsetAsync(cnt, 0, NB*sizeof(int), stream);
  gemm64_i8<3><<<6272, 128, 0, stream>>>(qi8,ND, mi8,ND, NM,ND,391,
      nullptr,0, q2,m2,thr, cand_d2,cand_idx,cnt);
  select50<<<NB, 256, 0, stream>>>(cand_d2, cand_idx, cnt, sel, dists, dsum);
  mean_kernel<<<1, 256, 0, stream>>>(dsum, meanbuf);

  // q-projection, then u[b,h,:] = Wk_h^T @ q_h  (collapses K-projection)
  gemm_uni<1><<<dim3(NB/128, ND/128, 1), 256, 0, stream>>>(qb,ND,0, wqb,ND,0, ND,ND,
      nullptr,qpb,ND,0, bq,0, nullptr,nullptr,0);
  gemm_uni<1><<<dim3(NB/128, ND/128, NH), 256, 0, stream>>>(qpb,ND,96, wkt,96,(long)ND*96, ND,96,
      nullptr,ubuf,NH*ND,ND, nullptr,0, nullptr,nullptr,0);

  // attention scores/softmax/weighted-neighbor-sum + rag prediction
  attn_kernel<<<NB, 256, 0, stream>>>(sel, mkeys, ubuf, dists, mvals, meanbuf, sbuf, out + (size_t)NB*ND);

  // ctx2[b,h*96+hd] = Wv_h @ s_h + bv   (collapses V-projection; exact since sum(attn)=1)
  gemm_uni<1><<<dim3(NB/128, 1, NH), 256, 0, stream>>>(sbuf,NH*ND,ND, wvb,ND,(long)96*ND, 96,ND,
      nullptr,ctx2b,ND,96, bv,96, nullptr,nullptr,0);

  // context = ctx2 @ Wo^T + bo; enhanced (f32) = query + context -> out; context -> combined[:,768:]
  gemm_uni<4><<<dim3(NB/128, ND/128, 1), 256, 0, stream>>>(ctx2b,ND,0, wob,ND,0, ND,ND,
      out,nullptr,ND,0, bo,0, query, comb+ND, 2*ND);

  // gate MLP
  gemm_uni<0><<<dim3(NB/128, 2, 1), 256, 0, stream>>>(comb,2*ND,0, wg1b,2*ND,0, 256,2*ND,
      hg,nullptr,256,0, bg1,0, nullptr,nullptr,0);
  gate2_kernel<<<NB/4, 256, 0, stream>>>(hg, Wg2, bg2, out + (size_t)NB*ND + NB);
}

// Round 9
// 762.005 us; speedup vs baseline: 1.5326x; 1.0411x over previous
//
#include <hip/hip_runtime.h>

typedef unsigned int u32;
typedef unsigned short u16;
typedef unsigned char u8;
typedef signed char s8;
typedef unsigned long long u64;
typedef __bf16 bf16x8 __attribute__((ext_vector_type(8)));
typedef float f32x4 __attribute__((ext_vector_type(4)));
typedef int i32x4 __attribute__((ext_vector_type(4)));

#define DEVI __device__ __forceinline__

DEVI u16 f2bf(float x){ u32 u = __builtin_bit_cast(u32, x); return (u16)((u + 0x7fffu + ((u>>16)&1u)) >> 16); }
DEVI float bf2f(u16 h){ return __builtin_bit_cast(float, ((u32)h)<<16); }
DEVI u32 qz(float x){ int i = (int)rintf(x*25.4f); i = i>127?127:(i<-127?-127:i); return (u32)(u8)(s8)i; }

// constants
#define NB 1024
#define ND 768
#define NM 50000
#define NK 50
#define NH 8
#define SAMP 4096
#define RSEL 25
#define CAP 2048
#define CAPX 256          // per-XCD-slice candidate capacity (expected ~38/slice)
#define S22 0.0031000062f // 2*(5/127)^2 : i8 scale^2 for the -2*q.m term

// ---------------- prep: wave-per-row f32 -> i8 (+ norms) ----------------
__global__ __launch_bounds__(256) void prep_mk(const float* __restrict__ src, s8* __restrict__ mi8,
                                               float* __restrict__ nrm2){
  int r = blockIdx.x*4 + (threadIdx.x>>6);
  int l = threadIdx.x & 63;
  const float4* s4 = (const float4*)(src + (long)r*ND);
  u32* di = (u32*)(mi8 + (long)r*ND);
  float ss = 0.f;
  #pragma unroll
  for (int j=0;j<3;j++){
    float4 v = s4[l + j*64];
    ss += v.x*v.x + v.y*v.y + v.z*v.z + v.w*v.w;
    di[l+j*64] = qz(v.x) | (qz(v.y)<<8) | (qz(v.z)<<16) | (qz(v.w)<<24);
  }
  #pragma unroll
  for (int o=32;o;o>>=1) ss += __shfl_down(ss,o);
  if (l==0) nrm2[r]=ss;
}

__global__ __launch_bounds__(256) void prep_query(const float* __restrict__ src, u16* __restrict__ qb,
                                                  float* __restrict__ q2, u16* __restrict__ comb,
                                                  s8* __restrict__ qi8){
  int r = blockIdx.x*4 + (threadIdx.x>>6);
  int l = threadIdx.x & 63;
  const float4* s4 = (const float4*)(src + (long)r*ND);
  u32* dq = (u32*)(qb + (long)r*ND);
  u32* dc = (u32*)(comb + (long)r*2*ND);
  u32* di = (u32*)(qi8 + (long)r*ND);
  float ss = 0.f;
  #pragma unroll
  for (int j=0;j<3;j++){
    float4 v = s4[l + j*64];
    ss += v.x*v.x + v.y*v.y + v.z*v.z + v.w*v.w;
    u32 p0 = ((u32)f2bf(v.y)<<16) | f2bf(v.x);
    u32 p1 = ((u32)f2bf(v.w)<<16) | f2bf(v.z);
    dq[(l+j*64)*2]=p0; dq[(l+j*64)*2+1]=p1;
    dc[(l+j*64)*2]=p0; dc[(l+j*64)*2+1]=p1;
    di[l+j*64] = qz(v.x) | (qz(v.y)<<8) | (qz(v.z)<<16) | (qz(v.w)<<24);
  }
  #pragma unroll
  for (int o=32;o;o>>=1) ss += __shfl_down(ss,o);
  if (l==0) q2[r]=ss;
}

__global__ void cvt_bf(const float* __restrict__ s, u16* __restrict__ d, int n){
  int i = blockIdx.x*256 + threadIdx.x;
  if (i<n) d[i] = f2bf(s[i]);
}

// wkt[h][d][hd] = Wk[h*96+hd][d]
__global__ void transpose_wk(const float* __restrict__ Wk, u16* __restrict__ wkt){
  int i = blockIdx.x*256 + threadIdx.x;
  if (i >= NH*ND*96) return;
  int h = i / (ND*96); int rem = i % (ND*96); int d = rem / 96; int hd = rem % 96;
  wkt[i] = f2bf(Wk[(long)(h*96+hd)*ND + d]);
}

// ============ i8 retrieval GEMM: 64x128 tile, K-step 64, 2 waves/block ============
// MODE 2: write d2.  MODE 3: threshold filter with BALLOT-AGGREGATED, XCD-SLICED append:
//   - cnt layout [cxcd][row]: each counter line touched by ONE XCD class -> no line ping-pong
//   - one atomicAdd(popcount) per 16-lane row-group instead of 16 dependent atomics
//   - candidates land in per-slice region cand[row][cxcd*CAPX + slot]
template<int MODE>
__global__ __launch_bounds__(128)
void gemm64_i8(const s8* __restrict__ A, int lda,
               const s8* __restrict__ Bm, int ldb,
               int Ndim, int Kbytes, int ny,
               float* __restrict__ Cf, int ldc,
               const float* __restrict__ q2, const float* __restrict__ m2, const float* __restrict__ thr,
               float* __restrict__ cand_d2, int* __restrict__ cand_idx, int* __restrict__ cnt)
{
  const int cxcd = blockIdx.x & 7; const int j = blockIdx.x >> 3;
  const int xt = j & 15, yhi = j >> 4;
  const int y = yhi*8 + cxcd;
  if (y >= ny) return;
  const int m0 = xt*64, n0 = y*128;

  const int t = threadIdx.x;
  const int lane = t & 63, w = t >> 6;
  __shared__ u8 As[64*64], Bs[128*64];
  i32x4 acc[2][8];
  #pragma unroll
  for (int m=0;m<2;m++)
    #pragma unroll
    for (int n=0;n<8;n++) acc[m][n] = i32x4{0,0,0,0};

  // staging: 128 threads; A 64 rows x 4 chunks (2/thread), B 128 rows x 4 chunks (4/thread)
  const int ra = t>>1, c0 = (t&1)*2;
  const int rb1 = ra+64;
  const int sw = (ra>>1)&3;
  const int s0 = ((c0  )^sw)*16, s1 = ((c0+1)^sw)*16;  // XOR-swizzled 16B chunk slots
  int jb0 = n0+ra;  if (jb0>=Ndim) jb0=Ndim-1;
  int jb1 = n0+rb1; if (jb1>=Ndim) jb1=Ndim-1;
  const s8* pa  = &A[(long)(m0+ra)*lda + c0*16];
  const s8* pb0 = &Bm[(long)jb0*ldb + c0*16];
  const s8* pb1 = &Bm[(long)jb1*ldb + c0*16];

  for (int k0=0; k0<Kbytes; k0+=64){
    __syncthreads();
    uint4 a0  = *(const uint4*)(pa  + k0);
    uint4 a1  = *(const uint4*)(pa  + k0 + 16);
    uint4 b00 = *(const uint4*)(pb0 + k0);
    uint4 b01 = *(const uint4*)(pb0 + k0 + 16);
    uint4 b10 = *(const uint4*)(pb1 + k0);
    uint4 b11 = *(const uint4*)(pb1 + k0 + 16);
    *(uint4*)&As[ra*64 + s0]  = a0;
    *(uint4*)&As[ra*64 + s1]  = a1;
    *(uint4*)&Bs[ra*64 + s0]  = b00;
    *(uint4*)&Bs[ra*64 + s1]  = b01;
    *(uint4*)&Bs[rb1*64 + s0] = b10;
    *(uint4*)&Bs[rb1*64 + s1] = b11;
    __syncthreads();
    i32x4 af[2], bfr[8];
    #pragma unroll
    for (int m=0;m<2;m++){
      int row = w*32 + m*16 + (lane&15);
      int slot = ((lane>>4) ^ ((row>>1)&3));
      af[m] = __builtin_bit_cast(i32x4, *(const uint4*)&As[row*64 + slot*16]);
    }
    #pragma unroll
    for (int n=0;n<8;n++){
      int row = n*16 + (lane&15);
      int slot = ((lane>>4) ^ ((row>>1)&3));
      bfr[n] = __builtin_bit_cast(i32x4, *(const uint4*)&Bs[row*64 + slot*16]);
    }
    #pragma unroll
    for (int m=0;m<2;m++)
      #pragma unroll
      for (int n=0;n<8;n++)
        acc[m][n] = __builtin_amdgcn_mfma_i32_16x16x64_i8(af[m], bfr[n], acc[m][n], 0,0,0);
  }

  const int g = lane>>4, li = lane&15;
  #pragma unroll
  for (int m=0;m<2;m++){
    #pragma unroll
    for (int q=0;q<4;q++){
      int r = m0 + w*32 + m*16 + (g<<2) + q;
      float qv = q2[r];
      float tv = (MODE==3) ? thr[r] : 0.f;
      #pragma unroll
      for (int n=0;n<8;n++){
        int c = n0 + n*16 + li;
        int cc = c < Ndim ? c : 0;
        float v = S22 * (float)acc[m][n][q];
        float d2 = fmaxf(qv+m2[cc]-v, 0.f);
        if (MODE==2){
          if (c<Ndim) Cf[(long)r*ldc + c] = d2;
        } else {
          bool hit = (c<Ndim) && (d2 <= tv);
          u64 mask = __ballot(hit);
          u32 bits = (u32)((mask >> (g*16)) & 0xffffull);
          int base = 0;
          if (li==0 && bits) base = atomicAdd(&cnt[cxcd*NB + r], (int)__popc(bits));
          base = __shfl(base, g*16);
          if (hit){
            int slot = base + (int)__popc(bits & ((1u<<li)-1u));
            if (slot < CAPX){
              cand_d2[(long)r*CAP + cxcd*CAPX + slot] = d2;
              cand_idx[(long)r*CAP + cxcd*CAPX + slot] = c;
            }
          }
        }
      }
    }
  }
}

// ============ unified bf16 A@B^T MFMA GEMM, 128x128x32 tile, 4 waves (projection GEMMs) ============
// MODE 0: C f32 = relu(acc + bias)         (gate hidden)
// MODE 1: C bf16 = acc + bias              (qp / u / ctx2)
// MODE 4: ctx = acc + bias; out2 = bf16(ctx); Cf f32 = qsrc + ctx  (Wo epilogue)
template<int MODE>
__global__ __launch_bounds__(256)
void gemm_uni(const u16* __restrict__ A, int lda, long az,
              const u16* __restrict__ Bm, int ldb, long bz,
              int Ndim, int Kdim,
              float* __restrict__ Cf, u16* __restrict__ Cb, int ldc, long cz,
              const float* __restrict__ bias, long biasz,
              const float* __restrict__ qsrc, u16* __restrict__ out2, int ldo2)
{
  const int m0 = blockIdx.x*128, n0 = blockIdx.y*128, z = blockIdx.z;
  A += (long)z*az; Bm += (long)z*bz;

  const int t = threadIdx.x;
  const int lane = t & 63, wid = t >> 6;
  __shared__ u16 As[2][128*32], Bs[2][128*32];
  f32x4 acc[4][4];
  #pragma unroll
  for (int m=0;m<4;m++)
    #pragma unroll
    for (int n=0;n<4;n++) acc[m][n] = f32x4{0.f,0.f,0.f,0.f};

  const int wr = (wid>>1)*64, wc = (wid&1)*64;
  const int sr = t>>2, sc4 = t&3;
  const int r0 = sr, r1 = sr+64;
  const int sl0 = (sc4 ^ ((r0>>1)&3))*8, sl1 = (sc4 ^ ((r1>>1)&3))*8;
  int jb0 = n0+r0; if (jb0>=Ndim) jb0=Ndim-1;
  int jb1 = n0+r1; if (jb1>=Ndim) jb1=Ndim-1;
  const u16* pa0 = &A[(long)(m0+r0)*lda + sc4*8];
  const u16* pa1 = &A[(long)(m0+r1)*lda + sc4*8];
  const u16* pb0 = &Bm[(long)jb0*ldb + sc4*8];
  const u16* pb1 = &Bm[(long)jb1*ldb + sc4*8];

  uint4 pA0,pA1,pB0,pB1, qA0,qA1,qB0,qB1;
  #define LOADG(S, K0) { S##A0 = *(const uint4*)(pa0+(K0)); S##A1 = *(const uint4*)(pa1+(K0)); \
                         S##B0 = *(const uint4*)(pb0+(K0)); S##B1 = *(const uint4*)(pb1+(K0)); }
  #define STORELDS(BUF, S) { *(uint4*)&As[BUF][r0*32+sl0] = S##A0; *(uint4*)&As[BUF][r1*32+sl1] = S##A1; \
                             *(uint4*)&Bs[BUF][r0*32+sl0] = S##B0; *(uint4*)&Bs[BUF][r1*32+sl1] = S##B1; }

  auto compute = [&](const u16* __restrict__ Ab, const u16* __restrict__ Bb){
    bf16x8 af[4], bfr[4];
    #pragma unroll
    for (int m=0;m<4;m++){
      int row = wr + m*16 + (lane&15);
      int slot = ((lane>>4) ^ ((row>>1)&3));
      af[m] = __builtin_bit_cast(bf16x8, *(const uint4*)&Ab[row*32 + slot*8]);
    }
    #pragma unroll
    for (int n=0;n<4;n++){
      int row = wc + n*16 + (lane&15);
      int slot = ((lane>>4) ^ ((row>>1)&3));
      bfr[n] = __builtin_bit_cast(bf16x8, *(const uint4*)&Bb[row*32 + slot*8]);
    }
    #pragma unroll
    for (int m=0;m<4;m++)
      #pragma unroll
      for (int n=0;n<4;n++)
        acc[m][n] = __builtin_amdgcn_mfma_f32_16x16x32_bf16(af[m], bfr[n], acc[m][n], 0,0,0);
  };

  const int nt = Kdim >> 5;
  LOADG(p, 0);
  if (nt > 1) LOADG(q, 32);
  #pragma unroll 1
  for (int ti=0; ti<nt; ti+=2){
    STORELDS(0, p);
    asm volatile("s_waitcnt lgkmcnt(0)" ::: "memory");
    __builtin_amdgcn_s_barrier();
    if (ti+2 < nt) LOADG(p, (ti+2)*32);
    compute(As[0], Bs[0]);
    if (ti+1 < nt){
      STORELDS(1, q);
      asm volatile("s_waitcnt lgkmcnt(0)" ::: "memory");
      __builtin_amdgcn_s_barrier();
      if (ti+3 < nt) LOADG(q, (ti+3)*32);
      compute(As[1], Bs[1]);
    }
  }
  #undef LOADG
  #undef STORELDS

  const float* bz_p = bias ? bias + (long)z*biasz : nullptr;
  #pragma unroll
  for (int m=0;m<4;m++){
    #pragma unroll
    for (int n=0;n<4;n++){
      #pragma unroll
      for (int q=0;q<4;q++){
        int r = m0 + wr + m*16 + ((lane>>4)<<2) + q;
        int c = n0 + wc + n*16 + (lane&15);
        float v = acc[m][n][q];
        if (MODE==0){
          if (c<Ndim){ if(bz_p) v += bz_p[c]; Cf[(long)r*ldc + (long)z*cz + c] = fmaxf(v,0.f); }
        } else if (MODE==1){
          if (c<Ndim){ if(bz_p) v += bz_p[c]; Cb[(long)r*ldc + (long)z*cz + c] = f2bf(v); }
        } else {
          if (c<Ndim){
            float ctx = v + (bz_p?bz_p[c]:0.f);
            out2[(long)r*ldo2 + c] = f2bf(ctx);
            Cf[(long)r*ldc + c] = qsrc[(long)r*ND+c] + ctx;   // enhanced, f32
          }
        }
      }
    }
  }
}

// ---------------- per-query threshold: per-wave bisection for 25th-smallest, min over waves ----------------
__global__ __launch_bounds__(256) void find_thr(const float* __restrict__ d2s, float* __restrict__ thr){
  int b = blockIdx.x, w = threadIdx.x>>6, l = threadIdx.x&63;
  const float4* base = (const float4*)(d2s + (long)b*SAMP + w*1024);
  float v[16];
  #pragma unroll
  for (int j=0;j<4;j++){
    float4 q = base[l*4+j];
    v[j*4]=q.x; v[j*4+1]=q.y; v[j*4+2]=q.z; v[j*4+3]=q.w;
  }
  u32 lo=0, hi=0x7f7fffffu;
  for (int it=0; it<28; ++it){
    u32 mid = (lo+hi)>>1;
    float fm = __builtin_bit_cast(float, mid);
    int c=0;
    #pragma unroll
    for (int j=0;j<16;j++) c += (v[j] <= fm) ? 1 : 0;
    #pragma unroll
    for (int o=32;o;o>>=1) c += __shfl_down(c,o);
    c = __shfl(c,0);
    if (c >= RSEL) hi = mid; else lo = mid+1;
  }
  __shared__ float wt[4];
  if (l==0) wt[w] = __builtin_bit_cast(float, hi);
  __syncthreads();
  if (threadIdx.x==0) thr[b] = fminf(fminf(wt[0],wt[1]), fminf(wt[2],wt[3]));
}

// ---------------- exact top-50: compact 8 slices, then parallel rank-count ----------------
__global__ __launch_bounds__(256) void select50(const float* __restrict__ cand_d2, const int* __restrict__ cand_idx,
                                                const int* __restrict__ cnt, int* __restrict__ sel,
                                                float* __restrict__ dists, float* __restrict__ dsum){
  int b = blockIdx.x, t = threadIdx.x;
  __shared__ u64 arr[CAP];
  __shared__ float dS[NK];
  __shared__ int cS[8], oS[9];
  if (t < 8){ int c = cnt[t*NB + b]; cS[t] = c > CAPX ? CAPX : c; }
  __syncthreads();
  if (t == 0){ oS[0]=0; for (int s=0;s<8;s++) oS[s+1]=oS[s]+cS[s]; }
  if (t < NK){ dS[t]=0.f; sel[b*NK+t]=0; dists[b*NK+t]=0.f; }  // safety init (n<50 ~impossible)
  __syncthreads();
  const int n = oS[8];
  for (int i=t;i<8*CAPX;i+=256){
    int s = i>>8, pos = i&(CAPX-1);
    if (pos < cS[s]){
      float d2 = fmaxf(cand_d2[(long)b*CAP + s*CAPX + pos],0.f);
      arr[oS[s]+pos] = ((u64)__builtin_bit_cast(u32, d2)<<32) | (u32)cand_idx[(long)b*CAP + s*CAPX + pos];
    }
  }
  __syncthreads();
  for (int i=t;i<n;i+=256){
    u64 me = arr[i];
    int rank = 0;
    for (int j=0;j<n;j++) rank += (arr[j] < me) ? 1 : 0;   // unique keys -> unique ranks
    if (rank < NK){
      float d = sqrtf(__builtin_bit_cast(float, (u32)(me>>32)));
      sel[b*NK+rank] = (int)(u32)(me & 0xffffffffu);
      dists[b*NK+rank] = d;
      dS[rank] = d;
    }
  }
  __syncthreads();
  if (t==0){ float s=0.f; for (int r=0;r<NK;r++) s+=dS[r]; dsum[b]=s; }
}

__global__ void mean_kernel(const float* __restrict__ dsum, float* __restrict__ meanbuf){
  int t = threadIdx.x;
  float s=0.f; for (int i=t;i<NB;i+=256) s += dsum[i];
  __shared__ float red[256];
  red[t]=s; __syncthreads();
  #pragma unroll
  for (int st=128;st>0;st>>=1){ if(t<st) red[t]+=red[t+st]; __syncthreads(); }
  if (t==0){ float mean = red[0]/(float)(NB*NK); meanbuf[0]=mean; meanbuf[1]=1.f/mean; }
}

// ---------------- per-query attention: online softmax, f32-source gathers, + rag ----------------
__global__ __launch_bounds__(256) void attn_kernel(
    const int* __restrict__ sel, const float* __restrict__ mk,
    const u16* __restrict__ ub, const float* __restrict__ dists,
    const float* __restrict__ mvals, const float* __restrict__ meanbuf,
    u16* __restrict__ sb, float* __restrict__ out_rag)
{
  const int b = blockIdx.x, t = threadIdx.x;
  __shared__ u16 nkS[25*772];
  __shared__ u16 uS[8*772];
  __shared__ float sc[NH*32];
  __shared__ float mh[NH], dh[NH], scS[NH];
  __shared__ int selS[NK];
  if (t < NK) selS[t] = sel[b*NK+t];
  if (t >= 64 && t < 64+NH){ mh[t-64] = -1e30f; dh[t-64] = 0.f; }
  {
    const u32* src = (const u32*)&ub[(long)b*NH*ND];
    for (int i=t;i<NH*(ND/2);i+=256){
      int h = i/(ND/2), d = i%(ND/2);
      ((u32*)&uS[h*772])[d] = src[h*(ND/2)+d];
    }
  }
  float sacc[3][NH];
  #pragma unroll
  for (int j=0;j<3;j++)
    #pragma unroll
    for (int h=0;h<NH;h++) sacc[j][h]=0.f;
  const float rs = 0.10206207261596575f;  // 1/sqrt(96)

  for (int half=0; half<2; ++half){
    __syncthreads();
    for (int k=0;k<25;k++){
      const float* src = &mk[(long)selS[half*25+k]*ND];
      for (int i=t;i<ND;i+=256) nkS[k*772+i] = f2bf(src[i]);
    }
    __syncthreads();
    if (t < 200){
      const u32* nr = (const u32*)&nkS[(t%25)*772];
      const u32* ur = (const u32*)&uS[(t/25)*772];
      float acc = 0.f;
      #pragma unroll 8
      for (int d=0; d<ND/2; d++){
        u32 a = nr[d], uu = ur[d];
        acc += bf2f((u16)a)*bf2f((u16)uu) + bf2f((u16)(a>>16))*bf2f((u16)(uu>>16));
      }
      sc[(t/25)*32 + (t%25)] = acc*rs;
    }
    __syncthreads();
    if (t < NH){
      float mn = mh[t];
      #pragma unroll
      for (int k=0;k<25;k++) mn = fmaxf(mn, sc[t*32+k]);
      float scale = __expf(mh[t]-mn);
      float d = dh[t]*scale;
      #pragma unroll
      for (int k=0;k<25;k++){ float e = __expf(sc[t*32+k]-mn); sc[t*32+k]=e; d+=e; }
      mh[t]=mn; dh[t]=d; scS[t]=scale;
    }
    __syncthreads();
    #pragma unroll
    for (int j=0;j<3;j++){
      int dd = t + j*256;
      #pragma unroll
      for (int h=0;h<NH;h++) sacc[j][h] *= scS[h];
      for (int k=0;k<25;k++){
        float nv = bf2f(nkS[k*772+dd]);
        float w0,w1,w2,w3,w4,w5,w6,w7;
        w0=sc[0*32+k]; w1=sc[1*32+k]; w2=sc[2*32+k]; w3=sc[3*32+k];
        w4=sc[4*32+k]; w5=sc[5*32+k]; w6=sc[6*32+k]; w7=sc[7*32+k];
        sacc[j][0]+=w0*nv; sacc[j][1]+=w1*nv; sacc[j][2]+=w2*nv; sacc[j][3]+=w3*nv;
        sacc[j][4]+=w4*nv; sacc[j][5]+=w5*nv; sacc[j][6]+=w6*nv; sacc[j][7]+=w7*nv;
      }
    }
  }
  float inv[NH];
  #pragma unroll
  for (int h=0;h<NH;h++) inv[h] = 1.f/dh[h];
  #pragma unroll
  for (int j=0;j<3;j++){
    int dd = t + j*256;
    #pragma unroll
    for (int h=0;h<NH;h++) sb[(long)b*NH*ND + h*ND + dd] = f2bf(sacc[j][h]*inv[h]);
  }
  if (t < 64){
    float num=0.f, den=0.f;
    if (t < NK){
      float d = dists[b*NK+t];
      float v = mvals[selS[t]];
      float e = __expf(-d*meanbuf[1]);
      num = e*v; den = e;
    }
    #pragma unroll
    for (int o=32;o;o>>=1){ num += __shfl_down(num,o); den += __shfl_down(den,o); }
    if (t==0) out_rag[b] = num/den;
  }
}

// ---------------- gate output ----------------
__global__ void gate2_kernel(const float* __restrict__ hg, const float* __restrict__ Wg2,
                             const float* __restrict__ bg2, float* __restrict__ outg){
  int b = blockIdx.x*4 + (threadIdx.x>>6);
  int l = threadIdx.x & 63;
  float s=0.f;
  for (int i=l;i<256;i+=64) s += hg[(long)b*256+i]*Wg2[i];
  #pragma unroll
  for (int o=32;o;o>>=1) s += __shfl_down(s,o);
  if (l==0) outg[b] = 1.f/(1.f+__expf(-(s+bg2[0])));
}

extern "C" void kernel_launch(void* const* d_in, const int* in_sizes, int n_in,
                              void* d_out, int out_size, void* d_ws, size_t ws_size,
                              hipStream_t stream){
  const float* query = (const float*)d_in[0];
  const float* mkeys = (const float*)d_in[1];
  const float* mvals = (const float*)d_in[2];
  const float* Wq  = (const float*)d_in[3];
  const float* bq  = (const float*)d_in[4];
  const float* Wk  = (const float*)d_in[5];
  const float* Wv  = (const float*)d_in[7];
  const float* bv  = (const float*)d_in[8];
  const float* Wo  = (const float*)d_in[9];
  const float* bo  = (const float*)d_in[10];
  const float* Wg1 = (const float*)d_in[11];
  const float* bg1 = (const float*)d_in[12];
  const float* Wg2 = (const float*)d_in[13];
  const float* bg2 = (const float*)d_in[14];
  float* out = (float*)d_out;           // f32: [enhanced B*768 | rag B | gate B]

  char* ws = (char*)d_ws;
  size_t off = 0;
  auto alloc = [&](size_t bytes)->char*{ char* p = ws + off; off += (bytes + 255) & ~(size_t)255; return p; };

  s8*    mi8   = (s8*)   alloc((size_t)NM*ND);
  s8*    qi8   = (s8*)   alloc((size_t)NB*ND);
  u16*   qb    = (u16*)  alloc((size_t)NB*ND*2);
  u16*   comb  = (u16*)  alloc((size_t)NB*2*ND*2);
  float* q2    = (float*)alloc(NB*4);
  float* m2    = (float*)alloc(NM*4);
  u16*   wqb   = (u16*)  alloc((size_t)ND*ND*2);
  u16*   wkt   = (u16*)  alloc((size_t)ND*ND*2);
  u16*   wvb   = (u16*)  alloc((size_t)ND*ND*2);
  u16*   wob   = (u16*)  alloc((size_t)ND*ND*2);
  u16*   wg1b  = (u16*)  alloc((size_t)256*2*ND*2);
  float* d2s   = (float*)alloc((size_t)NB*SAMP*4);   // aliased below by cand arrays (d2s dead after find_thr)
  float* thr   = (float*)alloc(NB*4);
  int*   cnt   = (int*)  alloc(8*NB*4);              // [cxcd][row]
  int*   sel   = (int*)  alloc((size_t)NB*NK*4);
  float* dists = (float*)alloc((size_t)NB*NK*4);
  float* dsum  = (float*)alloc(NB*4);
  float* meanbuf=(float*)alloc(256);
  u16*   qpb   = (u16*)  alloc((size_t)NB*ND*2);
  u16*   ubuf  = (u16*)  alloc((size_t)NB*NH*ND*2);
  u16*   sbuf  = (u16*)  alloc((size_t)NB*NH*ND*2);
  u16*   ctx2b = (u16*)  alloc((size_t)NB*ND*2);
  float* hg    = (float*)alloc((size_t)NB*256*4);
  // alias: cand buffers live in d2s region (16.8MB; cand needs 8.4+8.4MB); stream-ordered safe
  float* cand_d2 = d2s;
  int*   cand_idx= (int*)(d2s + (size_t)NB*CAP);
  (void)ws_size; (void)in_sizes; (void)n_in; (void)out_size;

  // prep
  prep_query<<<NB/4, 256, 0, stream>>>(query, qb, q2, comb, qi8);
  prep_mk<<<NM/4, 256, 0, stream>>>(mkeys, mi8, m2);
  cvt_bf<<<(ND*ND+255)/256, 256, 0, stream>>>(Wq, wqb, ND*ND);
  cvt_bf<<<(ND*ND+255)/256, 256, 0, stream>>>(Wv, wvb, ND*ND);
  cvt_bf<<<(ND*ND+255)/256, 256, 0, stream>>>(Wo, wob, ND*ND);
  cvt_bf<<<(256*2*ND+255)/256, 256, 0, stream>>>(Wg1, wg1b, 256*2*ND);
  transpose_wk<<<(ND*ND+255)/256, 256, 0, stream>>>(Wk, wkt);

  // retrieval: i8 sample -> threshold -> i8 filtered candidates -> exact top-50
  gemm64_i8<2><<<512, 128, 0, stream>>>(qi8,ND, mi8,ND, SAMP,ND,32,
      d2s,SAMP, q2,m2,nullptr, nullptr,nullptr,nullptr);
  find_thr<<<NB, 256, 0, stream>>>(d2s, thr);
  hipMemsetAsync(cnt, 0, 8*NB*sizeof(int), stream);
  gemm64_i8<3><<<6272, 128, 0, stream>>>(qi8,ND, mi8,ND, NM,ND,391,
      nullptr,0, q2,m2,thr, cand_d2,cand_idx,cnt);
  select50<<<NB, 256, 0, stream>>>(cand_d2, cand_idx, cnt, sel, dists, dsum);
  mean_kernel<<<1, 256, 0, stream>>>(dsum, meanbuf);

  // q-projection, then u[b,h,:] = Wk_h^T @ q_h  (collapses K-projection)
  gemm_uni<1><<<dim3(NB/128, ND/128, 1), 256, 0, stream>>>(qb,ND,0, wqb,ND,0, ND,ND,
      nullptr,qpb,ND,0, bq,0, nullptr,nullptr,0);
  gemm_uni<1><<<dim3(NB/128, ND/128, NH), 256, 0, stream>>>(qpb,ND,96, wkt,96,(long)ND*96, ND,96,
      nullptr,ubuf,NH*ND,ND, nullptr,0, nullptr,nullptr,0);

  // attention scores/softmax/weighted-neighbor-sum + rag prediction
  attn_kernel<<<NB, 256, 0, stream>>>(sel, mkeys, ubuf, dists, mvals, meanbuf, sbuf, out + (size_t)NB*ND);

  // ctx2[b,h*96+hd] = Wv_h @ s_h + bv   (collapses V-projection; exact since sum(attn)=1)
  gemm_uni<1><<<dim3(NB/128, 1, NH), 256, 0, stream>>>(sbuf,NH*ND,ND, wvb,ND,(long)96*ND, 96,ND,
      nullptr,ctx2b,ND,96, bv,96, nullptr,nullptr,0);

  // context = ctx2 @ Wo^T + bo; enhanced (f32) = query + context -> out; context -> combined[:,768:]
  gemm_uni<4><<<dim3(NB/128, ND/128, 1), 256, 0, stream>>>(ctx2b,ND,0, wob,ND,0, ND,ND,
      out,nullptr,ND,0, bo,0, query, comb+ND, 2*ND);

  // gate MLP
  gemm_uni<0><<<dim3(NB/128, 2, 1), 256, 0, stream>>>(comb,2*ND,0, wg1b,2*ND,0, 256,2*ND,
      hg,nullptr,256,0, bg1,0, nullptr,nullptr,0);
  gate2_kernel<<<NB/4, 256, 0, stream>>>(hg, Wg2, bg2, out + (size_t)NB*ND + NB);
}